// Round 3
// baseline (684.471 us; speedup 1.0000x reference)
//
#include <hip/hip_runtime.h>

#define NN   40000
#define EE   640000
#define DIN  127
#define HH   128
#define NSEGS 512
#define SEGSZ 64
#define NB_SCAN ((NN + 255) / 256)   // 157

// ---------------- h0 = concat(x, batch_indicator) ----------------
__global__ void build_h0(const float* __restrict__ x, float* __restrict__ h) {
    int t = blockIdx.x * 256 + threadIdx.x;
    if (t >= NN * HH) return;
    int i = t >> 7, d = t & 127;
    h[t] = (d < DIN) ? x[i * DIN + d] : 0.f;
}

__global__ void set_bf(const int* __restrict__ batches, float* __restrict__ h) {
    int j = blockIdx.x * 256 + threadIdx.x;
    if (j < NSEGS * SEGSZ) h[batches[j] * HH + DIN] = 1.0f;
}

// ---------------- CSR build ----------------
__global__ void zero_int(int* __restrict__ p, int n) {
    int t = blockIdx.x * 256 + threadIdx.x;
    if (t < n) p[t] = 0;
}

__global__ void count_deg(const int* __restrict__ ei, int* __restrict__ deg) {
    int e = blockIdx.x * 256 + threadIdx.x;
    if (e < EE) atomicAdd(&deg[ei[EE + e]], 1);
}

// phase 1: per-block (256 nodes) sums
__global__ __launch_bounds__(256) void scan_p1(const int* __restrict__ deg, int* __restrict__ bsum) {
    __shared__ int red[256];
    int t = threadIdx.x;
    int idx = blockIdx.x * 256 + t;
    red[t] = (idx < NN) ? deg[idx] : 0;
    __syncthreads();
#pragma unroll
    for (int off = 128; off > 0; off >>= 1) {
        if (t < off) red[t] += red[t + off];
        __syncthreads();
    }
    if (t == 0) bsum[blockIdx.x] = red[0];
}

// phase 2: single block, exclusive scan of NB_SCAN block sums (in place)
__global__ __launch_bounds__(256) void scan_p2(int* __restrict__ bsum) {
    __shared__ int s[256];
    int t = threadIdx.x;
    s[t] = (t < NB_SCAN) ? bsum[t] : 0;
    __syncthreads();
#pragma unroll
    for (int off = 1; off < 256; off <<= 1) {
        int x = (t >= off) ? s[t - off] : 0;
        __syncthreads();
        s[t] += x;
        __syncthreads();
    }
    if (t < NB_SCAN) bsum[t] = (t == 0) ? 0 : s[t - 1];
}

// phase 3: per-block local exclusive scan + block offset -> rowptr, fill
__global__ __launch_bounds__(256) void scan_p3(const int* __restrict__ deg, const int* __restrict__ bsum,
                                               int* __restrict__ rowptr, int* __restrict__ fill) {
    __shared__ int s[256];
    int t = threadIdx.x;
    int idx = blockIdx.x * 256 + t;
    int v = (idx < NN) ? deg[idx] : 0;
    s[t] = v;
    __syncthreads();
#pragma unroll
    for (int off = 1; off < 256; off <<= 1) {
        int x = (t >= off) ? s[t - off] : 0;
        __syncthreads();
        s[t] += x;
        __syncthreads();
    }
    int excl = bsum[blockIdx.x] + s[t] - v;
    if (idx < NN) { rowptr[idx] = excl; fill[idx] = excl; }
    if (idx == NN - 1) rowptr[NN] = excl + v;
}

__global__ void fill_csr(const int* __restrict__ ei, const float* __restrict__ ew,
                         int* __restrict__ fill, int* __restrict__ csr_src,
                         float* __restrict__ csr_w) {
    int e = blockIdx.x * 256 + threadIdx.x;
    if (e < EE) {
        int d = ei[EE + e];
        int pos = atomicAdd(&fill[d], 1);
        csr_src[pos] = ei[e];
        csr_w[pos] = ew[e];
    }
}

// ---------------- fused GIN layer: gather-aggregate into LDS, then GEMM+ReLU ----------------
// 512 threads = 8 waves per block; block owns 64 output rows.
// Phase A: wave per node, lane owns 2 columns; each edge = one coalesced 512B row read.
// Phase B: 4x4 register tile per thread; LDS reads are half-wave broadcasts.
__global__ __launch_bounds__(512, 4) void gin_layer(const float* __restrict__ h,
                                                    const int* __restrict__ rowptr,
                                                    const int* __restrict__ csr_src,
                                                    const float* __restrict__ csr_w,
                                                    const float* __restrict__ w,
                                                    const float* __restrict__ b,
                                                    float* __restrict__ hout) {
    __shared__ float lh[64 * 132];
    int row0 = blockIdx.x * 64;
    int tid = threadIdx.x;
    int wid = tid >> 6;      // 0..7
    int lane = tid & 63;
    int c = lane << 1;
    for (int i = wid; i < 64; i += 8) {
        int node = row0 + i;
        int beg = rowptr[node], end = rowptr[node + 1];
        float2 acc = *(const float2*)(h + (size_t)node * HH + c);   // self term
        for (int p = beg; p < end; ++p) {
            int s = csr_src[p];
            float wgt = csr_w[p];
            float2 v = *(const float2*)(h + (size_t)s * HH + c);
            acc.x += wgt * v.x;
            acc.y += wgt * v.y;
        }
        lh[i * 132 + c] = acc.x;
        lh[i * 132 + c + 1] = acc.y;
    }
    __syncthreads();

    int tc = tid & 31;       // cols: c0 = 4*tc
    int tr = tid >> 5;       // rows: tr + 16*j
    int c0 = tc << 2;
    float acc4[4][4];
#pragma unroll
    for (int j = 0; j < 4; j++)
        for (int q = 0; q < 4; q++) acc4[j][q] = 0.f;
    for (int k = 0; k < HH; k += 4) {
        float4 w0 = *(const float4*)(w + (k + 0) * HH + c0);
        float4 w1 = *(const float4*)(w + (k + 1) * HH + c0);
        float4 w2 = *(const float4*)(w + (k + 2) * HH + c0);
        float4 w3 = *(const float4*)(w + (k + 3) * HH + c0);
#pragma unroll
        for (int j = 0; j < 4; j++) {
            int r = tr + (j << 4);
            float4 hv = *(const float4*)(&lh[r * 132 + k]);
            acc4[j][0] += hv.x * w0.x + hv.y * w1.x + hv.z * w2.x + hv.w * w3.x;
            acc4[j][1] += hv.x * w0.y + hv.y * w1.y + hv.z * w2.y + hv.w * w3.y;
            acc4[j][2] += hv.x * w0.z + hv.y * w1.z + hv.z * w2.z + hv.w * w3.z;
            acc4[j][3] += hv.x * w0.w + hv.y * w1.w + hv.z * w2.w + hv.w * w3.w;
        }
    }
    float4 bv = *(const float4*)(b + c0);
#pragma unroll
    for (int j = 0; j < 4; j++) {
        int r = row0 + tr + (j << 4);
        float4 o;
        o.x = fmaxf(acc4[j][0] + bv.x, 0.f);
        o.y = fmaxf(acc4[j][1] + bv.y, 0.f);
        o.z = fmaxf(acc4[j][2] + bv.z, 0.f);
        o.w = fmaxf(acc4[j][3] + bv.w, 0.f);
        *(float4*)(hout + (size_t)r * HH + c0) = o;
    }
}

// ---------------- multipool ----------------
__global__ __launch_bounds__(128) void pool(const float* __restrict__ h,
                                            const int* __restrict__ batches,
                                            float* __restrict__ z) {
    int s = blockIdx.x, c = threadIdx.x;
    float sum = 0.f, mn = INFINITY, mx = -INFINITY;
    for (int j = 0; j < SEGSZ; j++) {
        int idx = batches[s * SEGSZ + j];
        float v = h[idx * HH + c];
        sum += v;
        mn = fminf(mn, v);
        mx = fmaxf(mx, v);
    }
    z[s * 384 + c] = sum * (1.f / SEGSZ);
    z[s * 384 + 128 + c] = mn;
    z[s * 384 + 256 + c] = mx;
}

// ---------------- readout MLP ----------------
__device__ __forceinline__ float block_sum(float v, float* red, int c) {
    red[c] = v;
    __syncthreads();
#pragma unroll
    for (int off = 64; off > 0; off >>= 1) {
        if (c < off) red[c] += red[c + off];
        __syncthreads();
    }
    float r = red[0];
    __syncthreads();
    return r;
}

__global__ __launch_bounds__(128) void readout(const float* __restrict__ z,
    const float* __restrict__ w1, const float* __restrict__ b1,
    const float* __restrict__ g1, const float* __restrict__ be1,
    const float* __restrict__ w2, const float* __restrict__ b2,
    const float* __restrict__ g2, const float* __restrict__ be2,
    const float* __restrict__ w3, const float* __restrict__ b3,
    float* __restrict__ out) {
    __shared__ float zr[384];
    __shared__ float red[128];
    __shared__ float v1[128];
    int s = blockIdx.x, c = threadIdx.x;
    for (int k = c; k < 384; k += 128) zr[k] = z[s * 384 + k];
    __syncthreads();

    float a = b1[c];
    for (int k = 0; k < 384; k++) a += zr[k] * w1[k * HH + c];
    a = fmaxf(a, 0.f);
    float m = block_sum(a, red, c) * (1.f / HH);
    float d = a - m;
    float var = block_sum(d * d, red, c) * (1.f / HH);
    float v = d * rsqrtf(var + 1e-5f) * g1[c] + be1[c];
    v1[c] = v;
    __syncthreads();

    float a2 = b2[c];
    for (int k = 0; k < HH; k++) a2 += v1[k] * w2[k * HH + c];
    float m2 = block_sum(a2, red, c) * (1.f / HH);
    float d2 = a2 - m2;
    float var2 = block_sum(d2 * d2, red, c) * (1.f / HH);
    float t2 = d2 * rsqrtf(var2 + 1e-5f) * g2[c] + be2[c];
    float z2 = fmaxf(t2, 0.f);

    float tot = block_sum(z2 * w3[c], red, c);
    if (c == 0) out[s] = tot + b3[0];
}

extern "C" void kernel_launch(void* const* d_in, const int* in_sizes, int n_in,
                              void* d_out, int out_size, void* d_ws, size_t ws_size,
                              hipStream_t stream) {
    const float* x        = (const float*)d_in[0];
    const int*   ei       = (const int*)d_in[1];
    const float* ew       = (const float*)d_in[2];
    const int*   batches  = (const int*)d_in[3];
    const float* gw[3]    = {(const float*)d_in[5], (const float*)d_in[7], (const float*)d_in[9]};
    const float* gb[3]    = {(const float*)d_in[6], (const float*)d_in[8], (const float*)d_in[10]};
    const float* r_w1 = (const float*)d_in[11]; const float* r_b1 = (const float*)d_in[12];
    const float* ln1g = (const float*)d_in[13]; const float* ln1b = (const float*)d_in[14];
    const float* r_w2 = (const float*)d_in[15]; const float* r_b2 = (const float*)d_in[16];
    const float* ln2g = (const float*)d_in[17]; const float* ln2b = (const float*)d_in[18];
    const float* r_w3 = (const float*)d_in[19]; const float* r_b3 = (const float*)d_in[20];
    float* out = (float*)d_out;

    // workspace layout
    float* h0    = (float*)d_ws;            // NN*HH
    float* h1    = h0 + (size_t)NN * HH;    // NN*HH
    float* z     = h1 + (size_t)NN * HH;    // NSEGS*384
    float* csr_w = z + (size_t)NSEGS * 384; // EE
    int* rowptr  = (int*)(csr_w + EE);      // NN+1
    int* deg     = rowptr + (NN + 1);       // NN
    int* fill    = deg + NN;                // NN
    int* csr_src = fill + NN;               // EE
    int* bsum    = csr_src + EE;            // NB_SCAN

    // CSR build (edges identical for all 3 layers)
    zero_int<<<(NN + 255) / 256, 256, 0, stream>>>(deg, NN);
    count_deg<<<(EE + 255) / 256, 256, 0, stream>>>(ei, deg);
    scan_p1<<<NB_SCAN, 256, 0, stream>>>(deg, bsum);
    scan_p2<<<1, 256, 0, stream>>>(bsum);
    scan_p3<<<NB_SCAN, 256, 0, stream>>>(deg, bsum, rowptr, fill);
    fill_csr<<<(EE + 255) / 256, 256, 0, stream>>>(ei, ew, fill, csr_src, csr_w);

    build_h0<<<(NN * HH + 255) / 256, 256, 0, stream>>>(x, h0);
    set_bf<<<(NSEGS * SEGSZ + 255) / 256, 256, 0, stream>>>(batches, h0);

    float* hin = h0;
    float* hout = h1;
    for (int l = 0; l < 3; l++) {
        gin_layer<<<NN / 64, 512, 0, stream>>>(hin, rowptr, csr_src, csr_w, gw[l], gb[l], hout);
        float* tmp = hin; hin = hout; hout = tmp;
    }

    pool<<<NSEGS, 128, 0, stream>>>(hin, batches, z);
    readout<<<NSEGS, 128, 0, stream>>>(z, r_w1, r_b1, ln1g, ln1b,
                                       r_w2, r_b2, ln2g, ln2b, r_w3, r_b3, out);
}

// Round 4
// 338.199 us; speedup vs baseline: 2.0239x; 2.0239x over previous
//
#include <hip/hip_runtime.h>

#define NN   40000
#define EE   640000
#define DIN  127
#define HH   128
#define NSEGS 512
#define SEGSZ 64
#define NB_SCAN ((NN + 255) / 256)   // 157

// ---------------- h0 = concat(x, batch_indicator) ----------------
__global__ void build_h0(const float* __restrict__ x, float* __restrict__ h) {
    int t = blockIdx.x * 256 + threadIdx.x;
    if (t >= NN * HH) return;
    int i = t >> 7, d = t & 127;
    h[t] = (d < DIN) ? x[i * DIN + d] : 0.f;
}

__global__ void set_bf(const int* __restrict__ batches, float* __restrict__ h) {
    int j = blockIdx.x * 256 + threadIdx.x;
    if (j < NSEGS * SEGSZ) h[batches[j] * HH + DIN] = 1.0f;
}

// ---------------- CSR build ----------------
__global__ void zero_int(int* __restrict__ p, int n) {
    int t = blockIdx.x * 256 + threadIdx.x;
    if (t < n) p[t] = 0;
}

__global__ void count_deg(const int* __restrict__ ei, int* __restrict__ deg) {
    int e = blockIdx.x * 256 + threadIdx.x;
    if (e < EE) atomicAdd(&deg[ei[EE + e]], 1);
}

__global__ __launch_bounds__(256) void scan_p1(const int* __restrict__ deg, int* __restrict__ bsum) {
    __shared__ int red[256];
    int t = threadIdx.x;
    int idx = blockIdx.x * 256 + t;
    red[t] = (idx < NN) ? deg[idx] : 0;
    __syncthreads();
#pragma unroll
    for (int off = 128; off > 0; off >>= 1) {
        if (t < off) red[t] += red[t + off];
        __syncthreads();
    }
    if (t == 0) bsum[blockIdx.x] = red[0];
}

__global__ __launch_bounds__(256) void scan_p2(int* __restrict__ bsum) {
    __shared__ int s[256];
    int t = threadIdx.x;
    s[t] = (t < NB_SCAN) ? bsum[t] : 0;
    __syncthreads();
#pragma unroll
    for (int off = 1; off < 256; off <<= 1) {
        int x = (t >= off) ? s[t - off] : 0;
        __syncthreads();
        s[t] += x;
        __syncthreads();
    }
    if (t < NB_SCAN) bsum[t] = (t == 0) ? 0 : s[t - 1];
}

__global__ __launch_bounds__(256) void scan_p3(const int* __restrict__ deg, const int* __restrict__ bsum,
                                               int* __restrict__ rowptr, int* __restrict__ fill) {
    __shared__ int s[256];
    int t = threadIdx.x;
    int idx = blockIdx.x * 256 + t;
    int v = (idx < NN) ? deg[idx] : 0;
    s[t] = v;
    __syncthreads();
#pragma unroll
    for (int off = 1; off < 256; off <<= 1) {
        int x = (t >= off) ? s[t - off] : 0;
        __syncthreads();
        s[t] += x;
        __syncthreads();
    }
    int excl = bsum[blockIdx.x] + s[t] - v;
    if (idx < NN) { rowptr[idx] = excl; fill[idx] = excl; }
    if (idx == NN - 1) rowptr[NN] = excl + v;
}

__global__ void fill_csr(const int* __restrict__ ei, const float* __restrict__ ew,
                         int* __restrict__ fill, int* __restrict__ csr_src,
                         float* __restrict__ csr_w) {
    int e = blockIdx.x * 256 + threadIdx.x;
    if (e < EE) {
        int d = ei[EE + e];
        int pos = atomicAdd(&fill[d], 1);
        csr_src[pos] = ei[e];
        csr_w[pos] = ew[e];
    }
}

// ---------------- aggregation: tb[n] = h[n] + sum_{e in CSR[n]} w_e * h[src_e] ----------------
// one wave per node, lane owns 2 columns; 4-edge unroll keeps 4 row-loads in flight
__global__ __launch_bounds__(256) void gin_agg(const float* __restrict__ h,
                                               const int* __restrict__ rowptr,
                                               const int* __restrict__ csr_src,
                                               const float* __restrict__ csr_w,
                                               float* __restrict__ outb) {
    int node = blockIdx.x * 4 + (threadIdx.x >> 6);
    if (node >= NN) return;
    int lane = threadIdx.x & 63;
    int c = lane << 1;
    int beg = rowptr[node], end = rowptr[node + 1];
    float2 acc = *(const float2*)(h + (size_t)node * HH + c);  // self term
    float2 acc2 = make_float2(0.f, 0.f);
    int p = beg;
    for (; p + 4 <= end; p += 4) {
        int s0 = csr_src[p + 0], s1 = csr_src[p + 1];
        int s2 = csr_src[p + 2], s3 = csr_src[p + 3];
        float w0 = csr_w[p + 0], w1 = csr_w[p + 1];
        float w2 = csr_w[p + 2], w3 = csr_w[p + 3];
        float2 v0 = *(const float2*)(h + (size_t)s0 * HH + c);
        float2 v1 = *(const float2*)(h + (size_t)s1 * HH + c);
        float2 v2 = *(const float2*)(h + (size_t)s2 * HH + c);
        float2 v3 = *(const float2*)(h + (size_t)s3 * HH + c);
        acc.x  += w0 * v0.x; acc.y  += w0 * v0.y;
        acc2.x += w1 * v1.x; acc2.y += w1 * v1.y;
        acc.x  += w2 * v2.x; acc.y  += w2 * v2.y;
        acc2.x += w3 * v3.x; acc2.y += w3 * v3.y;
    }
    for (; p < end; ++p) {
        int s = csr_src[p];
        float w = csr_w[p];
        float2 v = *(const float2*)(h + (size_t)s * HH + c);
        acc.x += w * v.x;
        acc.y += w * v.y;
    }
    acc.x += acc2.x;
    acc.y += acc2.y;
    *(float2*)(outb + (size_t)node * HH + c) = acc;
}

// ---------------- hout = relu(tin @ w + b), [NN,128]@[128,128] ----------------
__global__ __launch_bounds__(256) void gemm_relu(const float* __restrict__ tin,
                                                 const float* __restrict__ w,
                                                 const float* __restrict__ b,
                                                 float* __restrict__ hout) {
    __shared__ float lh[64 * 132];
    int row0 = blockIdx.x * 64;
    int tid = threadIdx.x;
    for (int idx = tid; idx < 64 * 32; idx += 256) {
        int r = idx >> 5, ch = (idx & 31) << 2;
        float4 v = *(const float4*)(tin + (row0 + r) * HH + ch);
        *(float4*)(&lh[r * 132 + ch]) = v;
    }
    __syncthreads();
    int tc = tid & 31;
    int tr = tid >> 5;
    int c0 = tc << 2;
    float acc[8][4];
#pragma unroll
    for (int j = 0; j < 8; j++)
        for (int q = 0; q < 4; q++) acc[j][q] = 0.f;
    for (int k = 0; k < HH; k += 4) {
        float4 w0 = *(const float4*)(w + (k + 0) * HH + c0);
        float4 w1 = *(const float4*)(w + (k + 1) * HH + c0);
        float4 w2 = *(const float4*)(w + (k + 2) * HH + c0);
        float4 w3 = *(const float4*)(w + (k + 3) * HH + c0);
#pragma unroll
        for (int j = 0; j < 8; j++) {
            int r = tr + (j << 3);
            float4 hv = *(const float4*)(&lh[r * 132 + k]);
            acc[j][0] += hv.x * w0.x + hv.y * w1.x + hv.z * w2.x + hv.w * w3.x;
            acc[j][1] += hv.x * w0.y + hv.y * w1.y + hv.z * w2.y + hv.w * w3.y;
            acc[j][2] += hv.x * w0.z + hv.y * w1.z + hv.z * w2.z + hv.w * w3.z;
            acc[j][3] += hv.x * w0.w + hv.y * w1.w + hv.z * w2.w + hv.w * w3.w;
        }
    }
    float4 bv = *(const float4*)(b + c0);
#pragma unroll
    for (int j = 0; j < 8; j++) {
        int r = row0 + tr + (j << 3);
        float4 o;
        o.x = fmaxf(acc[j][0] + bv.x, 0.f);
        o.y = fmaxf(acc[j][1] + bv.y, 0.f);
        o.z = fmaxf(acc[j][2] + bv.z, 0.f);
        o.w = fmaxf(acc[j][3] + bv.w, 0.f);
        *(float4*)(hout + (size_t)r * HH + c0) = o;
    }
}

// ---------------- multipool ----------------
__global__ __launch_bounds__(128) void pool(const float* __restrict__ h,
                                            const int* __restrict__ batches,
                                            float* __restrict__ z) {
    int s = blockIdx.x, c = threadIdx.x;
    float sum = 0.f, mn = INFINITY, mx = -INFINITY;
    for (int j = 0; j < SEGSZ; j++) {
        int idx = batches[s * SEGSZ + j];
        float v = h[idx * HH + c];
        sum += v;
        mn = fminf(mn, v);
        mx = fmaxf(mx, v);
    }
    z[s * 384 + c] = sum * (1.f / SEGSZ);
    z[s * 384 + 128 + c] = mn;
    z[s * 384 + 256 + c] = mx;
}

// ---------------- readout MLP ----------------
__device__ __forceinline__ float block_sum(float v, float* red, int c) {
    red[c] = v;
    __syncthreads();
#pragma unroll
    for (int off = 64; off > 0; off >>= 1) {
        if (c < off) red[c] += red[c + off];
        __syncthreads();
    }
    float r = red[0];
    __syncthreads();
    return r;
}

__global__ __launch_bounds__(128) void readout(const float* __restrict__ z,
    const float* __restrict__ w1, const float* __restrict__ b1,
    const float* __restrict__ g1, const float* __restrict__ be1,
    const float* __restrict__ w2, const float* __restrict__ b2,
    const float* __restrict__ g2, const float* __restrict__ be2,
    const float* __restrict__ w3, const float* __restrict__ b3,
    float* __restrict__ out) {
    __shared__ float zr[384];
    __shared__ float red[128];
    __shared__ float v1[128];
    int s = blockIdx.x, c = threadIdx.x;
    for (int k = c; k < 384; k += 128) zr[k] = z[s * 384 + k];
    __syncthreads();

    float a = b1[c];
    for (int k = 0; k < 384; k++) a += zr[k] * w1[k * HH + c];
    a = fmaxf(a, 0.f);
    float m = block_sum(a, red, c) * (1.f / HH);
    float d = a - m;
    float var = block_sum(d * d, red, c) * (1.f / HH);
    float v = d * rsqrtf(var + 1e-5f) * g1[c] + be1[c];
    v1[c] = v;
    __syncthreads();

    float a2 = b2[c];
    for (int k = 0; k < HH; k++) a2 += v1[k] * w2[k * HH + c];
    float m2 = block_sum(a2, red, c) * (1.f / HH);
    float d2 = a2 - m2;
    float var2 = block_sum(d2 * d2, red, c) * (1.f / HH);
    float t2 = d2 * rsqrtf(var2 + 1e-5f) * g2[c] + be2[c];
    float z2 = fmaxf(t2, 0.f);

    float tot = block_sum(z2 * w3[c], red, c);
    if (c == 0) out[s] = tot + b3[0];
}

extern "C" void kernel_launch(void* const* d_in, const int* in_sizes, int n_in,
                              void* d_out, int out_size, void* d_ws, size_t ws_size,
                              hipStream_t stream) {
    const float* x        = (const float*)d_in[0];
    const int*   ei       = (const int*)d_in[1];
    const float* ew       = (const float*)d_in[2];
    const int*   batches  = (const int*)d_in[3];
    const float* gw[3]    = {(const float*)d_in[5], (const float*)d_in[7], (const float*)d_in[9]};
    const float* gb[3]    = {(const float*)d_in[6], (const float*)d_in[8], (const float*)d_in[10]};
    const float* r_w1 = (const float*)d_in[11]; const float* r_b1 = (const float*)d_in[12];
    const float* ln1g = (const float*)d_in[13]; const float* ln1b = (const float*)d_in[14];
    const float* r_w2 = (const float*)d_in[15]; const float* r_b2 = (const float*)d_in[16];
    const float* ln2g = (const float*)d_in[17]; const float* ln2b = (const float*)d_in[18];
    const float* r_w3 = (const float*)d_in[19]; const float* r_b3 = (const float*)d_in[20];
    float* out = (float*)d_out;

    // workspace layout
    float* h0    = (float*)d_ws;            // NN*HH
    float* h1    = h0 + (size_t)NN * HH;    // NN*HH
    float* tb    = h1 + (size_t)NN * HH;    // NN*HH
    float* z     = tb + (size_t)NN * HH;    // NSEGS*384
    float* csr_w = z + (size_t)NSEGS * 384; // EE
    int* rowptr  = (int*)(csr_w + EE);      // NN+1
    int* deg     = rowptr + (NN + 1);       // NN
    int* fill    = deg + NN;                // NN
    int* csr_src = fill + NN;               // EE
    int* bsum    = csr_src + EE;            // NB_SCAN

    // CSR build (edges identical for all 3 layers)
    zero_int<<<(NN + 255) / 256, 256, 0, stream>>>(deg, NN);
    count_deg<<<(EE + 255) / 256, 256, 0, stream>>>(ei, deg);
    scan_p1<<<NB_SCAN, 256, 0, stream>>>(deg, bsum);
    scan_p2<<<1, 256, 0, stream>>>(bsum);
    scan_p3<<<NB_SCAN, 256, 0, stream>>>(deg, bsum, rowptr, fill);
    fill_csr<<<(EE + 255) / 256, 256, 0, stream>>>(ei, ew, fill, csr_src, csr_w);

    build_h0<<<(NN * HH + 255) / 256, 256, 0, stream>>>(x, h0);
    set_bf<<<(NSEGS * SEGSZ + 255) / 256, 256, 0, stream>>>(batches, h0);

    float* hin = h0;
    float* hout = h1;
    for (int l = 0; l < 3; l++) {
        gin_agg<<<(NN + 3) / 4, 256, 0, stream>>>(hin, rowptr, csr_src, csr_w, tb);
        gemm_relu<<<NN / 64, 256, 0, stream>>>(tb, gw[l], gb[l], hout);
        float* tmp = hin; hin = hout; hout = tmp;
    }

    pool<<<NSEGS, 128, 0, stream>>>(hin, batches, z);
    readout<<<NSEGS, 128, 0, stream>>>(z, r_w1, r_b1, ln1g, ln1b,
                                       r_w2, r_b2, ln2g, ln2b, r_w3, r_b3, out);
}

// Round 5
// 284.864 us; speedup vs baseline: 2.4028x; 1.1872x over previous
//
#include <hip/hip_runtime.h>

#define NN   40000
#define EE   640000
#define DIN  127
#define HH   128
#define NSEGS 512
#define SEGSZ 64
#define NB_SCAN ((NN + 255) / 256)   // 157

typedef unsigned int uint;
typedef unsigned short ushort;

__device__ __forceinline__ float bf2f(uint u16) {          // u16: low 16 bits hold bf16
    return __uint_as_float(u16 << 16);
}
__device__ __forceinline__ uint f2bf(float f) {            // RNE float->bf16 (low 16 bits)
    uint u = __float_as_uint(f);
    uint r = u + 0x7FFFu + ((u >> 16) & 1u);
    return r >> 16;
}

// ---------------- h0 = concat(x, batch_indicator) as bf16 ----------------
// one thread per uint (2 columns)
__global__ void build_h0(const float* __restrict__ x, uint* __restrict__ h) {
    int t = blockIdx.x * 256 + threadIdx.x;
    if (t >= NN * 64) return;
    int i = t >> 6, q = t & 63;
    int d0 = q << 1;                      // 0..126, always < DIN
    float a = x[i * DIN + d0];
    float b = (d0 + 1 < DIN) ? x[i * DIN + d0 + 1] : 0.f;
    h[t] = f2bf(a) | (f2bf(b) << 16);
}

__global__ void set_bf(const int* __restrict__ batches, ushort* __restrict__ h) {
    int j = blockIdx.x * 256 + threadIdx.x;
    if (j < NSEGS * SEGSZ) h[batches[j] * HH + DIN] = 0x3F80;   // bf16 1.0
}

// ---------------- CSR build ----------------
__global__ void zero_int(int* __restrict__ p, int n) {
    int t = blockIdx.x * 256 + threadIdx.x;
    if (t < n) p[t] = 0;
}

__global__ void count_deg(const int* __restrict__ ei, int* __restrict__ deg) {
    int e = blockIdx.x * 256 + threadIdx.x;
    if (e < EE) atomicAdd(&deg[ei[EE + e]], 1);
}

__global__ __launch_bounds__(256) void scan_p1(const int* __restrict__ deg, int* __restrict__ bsum) {
    __shared__ int red[256];
    int t = threadIdx.x;
    int idx = blockIdx.x * 256 + t;
    red[t] = (idx < NN) ? deg[idx] : 0;
    __syncthreads();
#pragma unroll
    for (int off = 128; off > 0; off >>= 1) {
        if (t < off) red[t] += red[t + off];
        __syncthreads();
    }
    if (t == 0) bsum[blockIdx.x] = red[0];
}

__global__ __launch_bounds__(256) void scan_p2(int* __restrict__ bsum) {
    __shared__ int s[256];
    int t = threadIdx.x;
    s[t] = (t < NB_SCAN) ? bsum[t] : 0;
    __syncthreads();
#pragma unroll
    for (int off = 1; off < 256; off <<= 1) {
        int x = (t >= off) ? s[t - off] : 0;
        __syncthreads();
        s[t] += x;
        __syncthreads();
    }
    if (t < NB_SCAN) bsum[t] = (t == 0) ? 0 : s[t - 1];
}

__global__ __launch_bounds__(256) void scan_p3(const int* __restrict__ deg, const int* __restrict__ bsum,
                                               int* __restrict__ rowptr, int* __restrict__ fill) {
    __shared__ int s[256];
    int t = threadIdx.x;
    int idx = blockIdx.x * 256 + t;
    int v = (idx < NN) ? deg[idx] : 0;
    s[t] = v;
    __syncthreads();
#pragma unroll
    for (int off = 1; off < 256; off <<= 1) {
        int x = (t >= off) ? s[t - off] : 0;
        __syncthreads();
        s[t] += x;
        __syncthreads();
    }
    int excl = bsum[blockIdx.x] + s[t] - v;
    if (idx < NN) { rowptr[idx] = excl; fill[idx] = excl; }
    if (idx == NN - 1) rowptr[NN] = excl + v;
}

__global__ void fill_csr(const int* __restrict__ ei, const float* __restrict__ ew,
                         int* __restrict__ fill, int* __restrict__ csr_src,
                         float* __restrict__ csr_w) {
    int e = blockIdx.x * 256 + threadIdx.x;
    if (e < EE) {
        int d = ei[EE + e];
        int pos = atomicAdd(&fill[d], 1);
        csr_src[pos] = ei[e];
        csr_w[pos] = ew[e];
    }
}

// ---------------- aggregation: tb[n] = h[n] + sum w_e * h[src_e]  (h bf16, acc fp32) ----------
// one wave per node; lane owns one uint = 2 columns; 4-edge unroll
__global__ __launch_bounds__(256) void gin_agg(const uint* __restrict__ h,
                                               const int* __restrict__ rowptr,
                                               const int* __restrict__ csr_src,
                                               const float* __restrict__ csr_w,
                                               float* __restrict__ outb) {
    int node = blockIdx.x * 4 + (threadIdx.x >> 6);
    if (node >= NN) return;
    int lane = threadIdx.x & 63;
    int beg = rowptr[node], end = rowptr[node + 1];
    uint self = h[(size_t)node * 64 + lane];
    float accx = bf2f(self & 0xffff), accy = bf2f(self >> 16);
    float bx = 0.f, by = 0.f;
    int p = beg;
    for (; p + 4 <= end; p += 4) {
        int s0 = csr_src[p + 0], s1 = csr_src[p + 1];
        int s2 = csr_src[p + 2], s3 = csr_src[p + 3];
        float w0 = csr_w[p + 0], w1 = csr_w[p + 1];
        float w2 = csr_w[p + 2], w3 = csr_w[p + 3];
        uint v0 = h[(size_t)s0 * 64 + lane];
        uint v1 = h[(size_t)s1 * 64 + lane];
        uint v2 = h[(size_t)s2 * 64 + lane];
        uint v3 = h[(size_t)s3 * 64 + lane];
        accx += w0 * bf2f(v0 & 0xffff); accy += w0 * bf2f(v0 >> 16);
        bx   += w1 * bf2f(v1 & 0xffff); by   += w1 * bf2f(v1 >> 16);
        accx += w2 * bf2f(v2 & 0xffff); accy += w2 * bf2f(v2 >> 16);
        bx   += w3 * bf2f(v3 & 0xffff); by   += w3 * bf2f(v3 >> 16);
    }
    for (; p < end; ++p) {
        int s = csr_src[p];
        float w = csr_w[p];
        uint v = h[(size_t)s * 64 + lane];
        accx += w * bf2f(v & 0xffff);
        accy += w * bf2f(v >> 16);
    }
    accx += bx;
    accy += by;
    int c = lane << 1;
    *(float2*)(outb + (size_t)node * HH + c) = make_float2(accx, accy);
}

// ---------------- hout(bf16) = relu(tin(fp32) @ w + b) ----------------
__global__ __launch_bounds__(256) void gemm_relu(const float* __restrict__ tin,
                                                 const float* __restrict__ w,
                                                 const float* __restrict__ b,
                                                 ushort* __restrict__ hout) {
    __shared__ float lh[64 * 132];
    int row0 = blockIdx.x * 64;
    int tid = threadIdx.x;
    for (int idx = tid; idx < 64 * 32; idx += 256) {
        int r = idx >> 5, ch = (idx & 31) << 2;
        float4 v = *(const float4*)(tin + (row0 + r) * HH + ch);
        *(float4*)(&lh[r * 132 + ch]) = v;
    }
    __syncthreads();
    int tc = tid & 31;
    int tr = tid >> 5;
    int c0 = tc << 2;
    float acc[8][4];
#pragma unroll
    for (int j = 0; j < 8; j++)
        for (int q = 0; q < 4; q++) acc[j][q] = 0.f;
    for (int k = 0; k < HH; k += 4) {
        float4 w0 = *(const float4*)(w + (k + 0) * HH + c0);
        float4 w1 = *(const float4*)(w + (k + 1) * HH + c0);
        float4 w2 = *(const float4*)(w + (k + 2) * HH + c0);
        float4 w3 = *(const float4*)(w + (k + 3) * HH + c0);
#pragma unroll
        for (int j = 0; j < 8; j++) {
            int r = tr + (j << 3);
            float4 hv = *(const float4*)(&lh[r * 132 + k]);
            acc[j][0] += hv.x * w0.x + hv.y * w1.x + hv.z * w2.x + hv.w * w3.x;
            acc[j][1] += hv.x * w0.y + hv.y * w1.y + hv.z * w2.y + hv.w * w3.y;
            acc[j][2] += hv.x * w0.z + hv.y * w1.z + hv.z * w2.z + hv.w * w3.z;
            acc[j][3] += hv.x * w0.w + hv.y * w1.w + hv.z * w2.w + hv.w * w3.w;
        }
    }
    float4 bv = *(const float4*)(b + c0);
#pragma unroll
    for (int j = 0; j < 8; j++) {
        int r = row0 + tr + (j << 3);
        float o0 = fmaxf(acc[j][0] + bv.x, 0.f);
        float o1 = fmaxf(acc[j][1] + bv.y, 0.f);
        float o2 = fmaxf(acc[j][2] + bv.z, 0.f);
        float o3 = fmaxf(acc[j][3] + bv.w, 0.f);
        uint2 o;
        o.x = f2bf(o0) | (f2bf(o1) << 16);
        o.y = f2bf(o2) | (f2bf(o3) << 16);
        *(uint2*)(hout + (size_t)r * HH + c0) = o;
    }
}

// ---------------- multipool (h bf16) ----------------
__global__ __launch_bounds__(128) void pool(const ushort* __restrict__ h,
                                            const int* __restrict__ batches,
                                            float* __restrict__ z) {
    int s = blockIdx.x, c = threadIdx.x;
    float sum = 0.f, mn = INFINITY, mx = -INFINITY;
    for (int j = 0; j < SEGSZ; j++) {
        int idx = batches[s * SEGSZ + j];
        float v = bf2f(h[(size_t)idx * HH + c]);
        sum += v;
        mn = fminf(mn, v);
        mx = fmaxf(mx, v);
    }
    z[s * 384 + c] = sum * (1.f / SEGSZ);
    z[s * 384 + 128 + c] = mn;
    z[s * 384 + 256 + c] = mx;
}

// ---------------- readout MLP ----------------
__device__ __forceinline__ float block_sum(float v, float* red, int c) {
    red[c] = v;
    __syncthreads();
#pragma unroll
    for (int off = 64; off > 0; off >>= 1) {
        if (c < off) red[c] += red[c + off];
        __syncthreads();
    }
    float r = red[0];
    __syncthreads();
    return r;
}

__global__ __launch_bounds__(128) void readout(const float* __restrict__ z,
    const float* __restrict__ w1, const float* __restrict__ b1,
    const float* __restrict__ g1, const float* __restrict__ be1,
    const float* __restrict__ w2, const float* __restrict__ b2,
    const float* __restrict__ g2, const float* __restrict__ be2,
    const float* __restrict__ w3, const float* __restrict__ b3,
    float* __restrict__ out) {
    __shared__ float zr[384];
    __shared__ float red[128];
    __shared__ float v1[128];
    int s = blockIdx.x, c = threadIdx.x;
    for (int k = c; k < 384; k += 128) zr[k] = z[s * 384 + k];
    __syncthreads();

    float a = b1[c];
    for (int k = 0; k < 384; k++) a += zr[k] * w1[k * HH + c];
    a = fmaxf(a, 0.f);
    float m = block_sum(a, red, c) * (1.f / HH);
    float d = a - m;
    float var = block_sum(d * d, red, c) * (1.f / HH);
    float v = d * rsqrtf(var + 1e-5f) * g1[c] + be1[c];
    v1[c] = v;
    __syncthreads();

    float a2 = b2[c];
    for (int k = 0; k < HH; k++) a2 += v1[k] * w2[k * HH + c];
    float m2 = block_sum(a2, red, c) * (1.f / HH);
    float d2 = a2 - m2;
    float var2 = block_sum(d2 * d2, red, c) * (1.f / HH);
    float t2 = d2 * rsqrtf(var2 + 1e-5f) * g2[c] + be2[c];
    float z2 = fmaxf(t2, 0.f);

    float tot = block_sum(z2 * w3[c], red, c);
    if (c == 0) out[s] = tot + b3[0];
}

extern "C" void kernel_launch(void* const* d_in, const int* in_sizes, int n_in,
                              void* d_out, int out_size, void* d_ws, size_t ws_size,
                              hipStream_t stream) {
    const float* x        = (const float*)d_in[0];
    const int*   ei       = (const int*)d_in[1];
    const float* ew       = (const float*)d_in[2];
    const int*   batches  = (const int*)d_in[3];
    const float* gw[3]    = {(const float*)d_in[5], (const float*)d_in[7], (const float*)d_in[9]};
    const float* gb[3]    = {(const float*)d_in[6], (const float*)d_in[8], (const float*)d_in[10]};
    const float* r_w1 = (const float*)d_in[11]; const float* r_b1 = (const float*)d_in[12];
    const float* ln1g = (const float*)d_in[13]; const float* ln1b = (const float*)d_in[14];
    const float* r_w2 = (const float*)d_in[15]; const float* r_b2 = (const float*)d_in[16];
    const float* ln2g = (const float*)d_in[17]; const float* ln2b = (const float*)d_in[18];
    const float* r_w3 = (const float*)d_in[19]; const float* r_b3 = (const float*)d_in[20];
    float* out = (float*)d_out;

    // workspace layout (h0/h1 are bf16 = NN*64 uints each)
    uint*  h0    = (uint*)d_ws;               // NN*64 uints
    uint*  h1    = h0 + (size_t)NN * 64;      // NN*64 uints
    float* tb    = (float*)(h1 + (size_t)NN * 64);  // NN*HH fp32
    float* z     = tb + (size_t)NN * HH;      // NSEGS*384
    float* csr_w = z + (size_t)NSEGS * 384;   // EE
    int* rowptr  = (int*)(csr_w + EE);        // NN+1
    int* deg     = rowptr + (NN + 1);         // NN
    int* fill    = deg + NN;                  // NN
    int* csr_src = fill + NN;                 // EE
    int* bsum    = csr_src + EE;              // NB_SCAN

    // CSR build (edges identical for all 3 layers)
    zero_int<<<(NN + 255) / 256, 256, 0, stream>>>(deg, NN);
    count_deg<<<(EE + 255) / 256, 256, 0, stream>>>(ei, deg);
    scan_p1<<<NB_SCAN, 256, 0, stream>>>(deg, bsum);
    scan_p2<<<1, 256, 0, stream>>>(bsum);
    scan_p3<<<NB_SCAN, 256, 0, stream>>>(deg, bsum, rowptr, fill);
    fill_csr<<<(EE + 255) / 256, 256, 0, stream>>>(ei, ew, fill, csr_src, csr_w);

    build_h0<<<(NN * 64 + 255) / 256, 256, 0, stream>>>(x, h0);
    set_bf<<<(NSEGS * SEGSZ + 255) / 256, 256, 0, stream>>>(batches, (ushort*)h0);

    uint* hin = h0;
    uint* hout = h1;
    for (int l = 0; l < 3; l++) {
        gin_agg<<<(NN + 3) / 4, 256, 0, stream>>>(hin, rowptr, csr_src, csr_w, tb);
        gemm_relu<<<NN / 64, 256, 0, stream>>>(tb, gw[l], gb[l], (ushort*)hout);
        uint* tmp = hin; hin = hout; hout = tmp;
    }

    pool<<<NSEGS, 128, 0, stream>>>((const ushort*)hin, batches, z);
    readout<<<NSEGS, 128, 0, stream>>>(z, r_w1, r_b1, ln1g, ln1b,
                                       r_w2, r_b2, ln2g, ln2b, r_w3, r_b3, out);
}

// Round 6
// 240.803 us; speedup vs baseline: 2.8425x; 1.1830x over previous
//
#include <hip/hip_runtime.h>
#include <hip/hip_fp16.h>

#define NN   40000
#define EE   640000
#define DIN  127
#define HH   128
#define NSEGS 512
#define SEGSZ 64
#define CAP  64          // ELL row capacity (avg deg 16, std 4 -> safe)

typedef unsigned int uint;
typedef unsigned short ushort;

__device__ __forceinline__ float h2f_lo(uint v) {
    __half_raw r; r.x = (ushort)(v & 0xffff); return __half2float(__half(r));
}
__device__ __forceinline__ float h2f_hi(uint v) {
    __half_raw r; r.x = (ushort)(v >> 16); return __half2float(__half(r));
}
__device__ __forceinline__ ushort f2h(float f) {
    __half h = __float2half(f);
    return __half_as_ushort(h);
}

// ---------------- h0 = concat(x, batch_indicator) as fp16 ----------------
__global__ void build_h0(const float* __restrict__ x, uint* __restrict__ h) {
    int t = blockIdx.x * 256 + threadIdx.x;
    if (t >= NN * 64) return;
    int i = t >> 6, q = t & 63;
    int d0 = q << 1;                      // 0..126
    float a = x[i * DIN + d0];
    float b = (d0 + 1 < DIN) ? x[i * DIN + d0 + 1] : 0.f;
    h[t] = (uint)f2h(a) | ((uint)f2h(b) << 16);
}

__global__ void set_bf(const int* __restrict__ batches, ushort* __restrict__ h) {
    int j = blockIdx.x * 256 + threadIdx.x;
    if (j < NSEGS * SEGSZ) h[(size_t)batches[j] * HH + DIN] = 0x3C00;   // fp16 1.0
}

// ---------------- ELL build: single pass over edges ----------------
__global__ void zero_int(int* __restrict__ p, int n) {
    int t = blockIdx.x * 256 + threadIdx.x;
    if (t < n) p[t] = 0;
}

__global__ void ell_fill(const int* __restrict__ ei, const float* __restrict__ ew,
                         int* __restrict__ cnt, int2* __restrict__ ell) {
    int e = blockIdx.x * 256 + threadIdx.x;
    if (e >= EE) return;
    int d = ei[EE + e];
    int slot = atomicAdd(&cnt[d], 1);
    if (slot < CAP)
        ell[(size_t)d * CAP + slot] = make_int2(ei[e], __float_as_int(ew[e]));
}

// ---------------- aggregation: tb[n] = h[n] + sum w_e * h[src_e]  (h fp16, acc fp32) --------
// one wave per node; lane owns one uint = 2 columns; 4-edge unroll
__global__ __launch_bounds__(256) void gin_agg(const uint* __restrict__ h,
                                               const int* __restrict__ cnt,
                                               const int2* __restrict__ ell,
                                               float* __restrict__ outb) {
    int node = blockIdx.x * 4 + (threadIdx.x >> 6);
    if (node >= NN) return;
    int lane = threadIdx.x & 63;
    int n = cnt[node];
    if (n > CAP) n = CAP;
    const int2* row = ell + (size_t)node * CAP;
    uint self = h[(size_t)node * 64 + lane];
    float accx = h2f_lo(self), accy = h2f_hi(self);
    float bx = 0.f, by = 0.f;
    int p = 0;
    for (; p + 4 <= n; p += 4) {
        int2 e0 = row[p + 0], e1 = row[p + 1], e2 = row[p + 2], e3 = row[p + 3];
        float w0 = __int_as_float(e0.y), w1 = __int_as_float(e1.y);
        float w2 = __int_as_float(e2.y), w3 = __int_as_float(e3.y);
        uint v0 = h[(size_t)e0.x * 64 + lane];
        uint v1 = h[(size_t)e1.x * 64 + lane];
        uint v2 = h[(size_t)e2.x * 64 + lane];
        uint v3 = h[(size_t)e3.x * 64 + lane];
        accx += w0 * h2f_lo(v0); accy += w0 * h2f_hi(v0);
        bx   += w1 * h2f_lo(v1); by   += w1 * h2f_hi(v1);
        accx += w2 * h2f_lo(v2); accy += w2 * h2f_hi(v2);
        bx   += w3 * h2f_lo(v3); by   += w3 * h2f_hi(v3);
    }
    for (; p < n; ++p) {
        int2 e = row[p];
        float w = __int_as_float(e.y);
        uint v = h[(size_t)e.x * 64 + lane];
        accx += w * h2f_lo(v);
        accy += w * h2f_hi(v);
    }
    accx += bx;
    accy += by;
    int c = lane << 1;
    *(float2*)(outb + (size_t)node * HH + c) = make_float2(accx, accy);
}

// ---------------- hout(fp16) = relu(tin(fp32) @ w + b) ----------------
__global__ __launch_bounds__(256) void gemm_relu(const float* __restrict__ tin,
                                                 const float* __restrict__ w,
                                                 const float* __restrict__ b,
                                                 ushort* __restrict__ hout) {
    __shared__ float lh[64 * 132];
    int row0 = blockIdx.x * 64;
    int tid = threadIdx.x;
    for (int idx = tid; idx < 64 * 32; idx += 256) {
        int r = idx >> 5, ch = (idx & 31) << 2;
        float4 v = *(const float4*)(tin + (size_t)(row0 + r) * HH + ch);
        *(float4*)(&lh[r * 132 + ch]) = v;
    }
    __syncthreads();
    int tc = tid & 31;
    int tr = tid >> 5;
    int c0 = tc << 2;
    float acc[8][4];
#pragma unroll
    for (int j = 0; j < 8; j++)
        for (int q = 0; q < 4; q++) acc[j][q] = 0.f;
    for (int k = 0; k < HH; k += 4) {
        float4 w0 = *(const float4*)(w + (k + 0) * HH + c0);
        float4 w1 = *(const float4*)(w + (k + 1) * HH + c0);
        float4 w2 = *(const float4*)(w + (k + 2) * HH + c0);
        float4 w3 = *(const float4*)(w + (k + 3) * HH + c0);
#pragma unroll
        for (int j = 0; j < 8; j++) {
            int r = tr + (j << 3);
            float4 hv = *(const float4*)(&lh[r * 132 + k]);
            acc[j][0] += hv.x * w0.x + hv.y * w1.x + hv.z * w2.x + hv.w * w3.x;
            acc[j][1] += hv.x * w0.y + hv.y * w1.y + hv.z * w2.y + hv.w * w3.y;
            acc[j][2] += hv.x * w0.z + hv.y * w1.z + hv.z * w2.z + hv.w * w3.z;
            acc[j][3] += hv.x * w0.w + hv.y * w1.w + hv.z * w2.w + hv.w * w3.w;
        }
    }
    float4 bv = *(const float4*)(b + c0);
#pragma unroll
    for (int j = 0; j < 8; j++) {
        int r = row0 + tr + (j << 3);
        float o0 = fmaxf(acc[j][0] + bv.x, 0.f);
        float o1 = fmaxf(acc[j][1] + bv.y, 0.f);
        float o2 = fmaxf(acc[j][2] + bv.z, 0.f);
        float o3 = fmaxf(acc[j][3] + bv.w, 0.f);
        uint2 o;
        o.x = (uint)f2h(o0) | ((uint)f2h(o1) << 16);
        o.y = (uint)f2h(o2) | ((uint)f2h(o3) << 16);
        *(uint2*)(hout + (size_t)r * HH + c0) = o;
    }
}

// ---------------- multipool (h fp16) ----------------
__global__ __launch_bounds__(128) void pool(const ushort* __restrict__ h,
                                            const int* __restrict__ batches,
                                            float* __restrict__ z) {
    int s = blockIdx.x, c = threadIdx.x;
    float sum = 0.f, mn = INFINITY, mx = -INFINITY;
    for (int j = 0; j < SEGSZ; j++) {
        int idx = batches[s * SEGSZ + j];
        __half_raw r; r.x = h[(size_t)idx * HH + c];
        float v = __half2float(__half(r));
        sum += v;
        mn = fminf(mn, v);
        mx = fmaxf(mx, v);
    }
    z[s * 384 + c] = sum * (1.f / SEGSZ);
    z[s * 384 + 128 + c] = mn;
    z[s * 384 + 256 + c] = mx;
}

// ---------------- readout MLP ----------------
__device__ __forceinline__ float block_sum(float v, float* red, int c) {
    red[c] = v;
    __syncthreads();
#pragma unroll
    for (int off = 64; off > 0; off >>= 1) {
        if (c < off) red[c] += red[c + off];
        __syncthreads();
    }
    float r = red[0];
    __syncthreads();
    return r;
}

__global__ __launch_bounds__(128) void readout(const float* __restrict__ z,
    const float* __restrict__ w1, const float* __restrict__ b1,
    const float* __restrict__ g1, const float* __restrict__ be1,
    const float* __restrict__ w2, const float* __restrict__ b2,
    const float* __restrict__ g2, const float* __restrict__ be2,
    const float* __restrict__ w3, const float* __restrict__ b3,
    float* __restrict__ out) {
    __shared__ float zr[384];
    __shared__ float red[128];
    __shared__ float v1[128];
    int s = blockIdx.x, c = threadIdx.x;
    for (int k = c; k < 384; k += 128) zr[k] = z[s * 384 + k];
    __syncthreads();

    float a = b1[c];
    for (int k = 0; k < 384; k++) a += zr[k] * w1[k * HH + c];
    a = fmaxf(a, 0.f);
    float m = block_sum(a, red, c) * (1.f / HH);
    float d = a - m;
    float var = block_sum(d * d, red, c) * (1.f / HH);
    float v = d * rsqrtf(var + 1e-5f) * g1[c] + be1[c];
    v1[c] = v;
    __syncthreads();

    float a2 = b2[c];
    for (int k = 0; k < HH; k++) a2 += v1[k] * w2[k * HH + c];
    float m2 = block_sum(a2, red, c) * (1.f / HH);
    float d2 = a2 - m2;
    float var2 = block_sum(d2 * d2, red, c) * (1.f / HH);
    float t2 = d2 * rsqrtf(var2 + 1e-5f) * g2[c] + be2[c];
    float z2 = fmaxf(t2, 0.f);

    float tot = block_sum(z2 * w3[c], red, c);
    if (c == 0) out[s] = tot + b3[0];
}

extern "C" void kernel_launch(void* const* d_in, const int* in_sizes, int n_in,
                              void* d_out, int out_size, void* d_ws, size_t ws_size,
                              hipStream_t stream) {
    const float* x        = (const float*)d_in[0];
    const int*   ei       = (const int*)d_in[1];
    const float* ew       = (const float*)d_in[2];
    const int*   batches  = (const int*)d_in[3];
    const float* gw[3]    = {(const float*)d_in[5], (const float*)d_in[7], (const float*)d_in[9]};
    const float* gb[3]    = {(const float*)d_in[6], (const float*)d_in[8], (const float*)d_in[10]};
    const float* r_w1 = (const float*)d_in[11]; const float* r_b1 = (const float*)d_in[12];
    const float* ln1g = (const float*)d_in[13]; const float* ln1b = (const float*)d_in[14];
    const float* r_w2 = (const float*)d_in[15]; const float* r_b2 = (const float*)d_in[16];
    const float* ln2g = (const float*)d_in[17]; const float* ln2b = (const float*)d_in[18];
    const float* r_w3 = (const float*)d_in[19]; const float* r_b3 = (const float*)d_in[20];
    float* out = (float*)d_out;

    // workspace layout
    uint*  h0   = (uint*)d_ws;                       // NN*64 uints (fp16 x2)
    uint*  h1   = h0 + (size_t)NN * 64;              // NN*64 uints
    float* tb   = (float*)(h1 + (size_t)NN * 64);    // NN*HH fp32
    float* z    = tb + (size_t)NN * HH;              // NSEGS*384
    int2*  ell  = (int2*)(z + (size_t)NSEGS * 384);  // NN*CAP int2
    int*   cnt  = (int*)(ell + (size_t)NN * CAP);    // NN

    zero_int<<<(NN + 255) / 256, 256, 0, stream>>>(cnt, NN);
    ell_fill<<<(EE + 255) / 256, 256, 0, stream>>>(ei, ew, cnt, ell);

    build_h0<<<(NN * 64 + 255) / 256, 256, 0, stream>>>(x, h0);
    set_bf<<<(NSEGS * SEGSZ + 255) / 256, 256, 0, stream>>>(batches, (ushort*)h0);

    uint* hin = h0;
    uint* hout = h1;
    for (int l = 0; l < 3; l++) {
        gin_agg<<<(NN + 3) / 4, 256, 0, stream>>>(hin, cnt, ell, tb);
        gemm_relu<<<NN / 64, 256, 0, stream>>>(tb, gw[l], gb[l], (ushort*)hout);
        uint* tmp = hin; hin = hout; hout = tmp;
    }

    pool<<<NSEGS, 128, 0, stream>>>((const ushort*)hin, batches, z);
    readout<<<NSEGS, 128, 0, stream>>>(z, r_w1, r_b1, ln1g, ln1b,
                                       r_w2, r_b2, ln2g, ln2b, r_w3, r_b3, out);
}

// Round 7
// 213.812 us; speedup vs baseline: 3.2013x; 1.1262x over previous
//
#include <hip/hip_runtime.h>
#include <hip/hip_fp16.h>

#define NN   40000
#define EE   640000
#define DIN  127
#define HH   128
#define NSEGS 512
#define SEGSZ 64
#define CAP  64          // ELL row capacity (avg deg 16, Poisson tail ~0 at 64)

typedef unsigned int uint;
typedef unsigned short ushort;
typedef _Float16 f16;
typedef __attribute__((ext_vector_type(8))) _Float16 f16x8;
typedef __attribute__((ext_vector_type(4))) float f32x4;

__device__ __forceinline__ float h2f_lo(uint v) {
    __half_raw r; r.x = (ushort)(v & 0xffff); return __half2float(__half(r));
}
__device__ __forceinline__ float h2f_hi(uint v) {
    __half_raw r; r.x = (ushort)(v >> 16); return __half2float(__half(r));
}
__device__ __forceinline__ ushort f2h(float f) {
    return __half_as_ushort(__float2half(f));
}

// ---------------- h0 = concat(x, batch_indicator) as fp16 ----------------
__global__ void build_h0(const float* __restrict__ x, uint* __restrict__ h) {
    int t = blockIdx.x * 256 + threadIdx.x;
    if (t >= NN * 64) return;
    int i = t >> 6, q = t & 63;
    int d0 = q << 1;                      // 0..126
    float a = x[i * DIN + d0];
    float b = (d0 + 1 < DIN) ? x[i * DIN + d0 + 1] : 0.f;
    h[t] = (uint)f2h(a) | ((uint)f2h(b) << 16);
}

__global__ void set_bf(const int* __restrict__ batches, ushort* __restrict__ h) {
    int j = blockIdx.x * 256 + threadIdx.x;
    if (j < NSEGS * SEGSZ) h[(size_t)batches[j] * HH + DIN] = 0x3C00;   // fp16 1.0
}

// ---------------- weights fp32 [K][N] -> fp16 N-major [N][K] (B^T) ----------------
__global__ void wcvt(const float* __restrict__ w0, const float* __restrict__ w1,
                     const float* __restrict__ w2, ushort* __restrict__ wp) {
    int t = blockIdx.x * 256 + threadIdx.x;
    if (t >= 3 * HH * HH) return;
    int l = t / (HH * HH);
    int r = t - l * (HH * HH);
    int n = r >> 7, k = r & 127;
    const float* w = (l == 0) ? w0 : (l == 1) ? w1 : w2;
    wp[t] = f2h(w[k * HH + n]);
}

// ---------------- ELL build: single pass over edges ----------------
__global__ void zero_int(int* __restrict__ p, int n) {
    int t = blockIdx.x * 256 + threadIdx.x;
    if (t < n) p[t] = 0;
}

__global__ void ell_fill(const int* __restrict__ ei, const float* __restrict__ ew,
                         int* __restrict__ cnt, int2* __restrict__ ell) {
    int e = blockIdx.x * 256 + threadIdx.x;
    if (e >= EE) return;
    int d = ei[EE + e];
    int slot = atomicAdd(&cnt[d], 1);
    if (slot < CAP)
        ell[(size_t)d * CAP + slot] = make_int2(ei[e], __float_as_int(ew[e]));
}

// ---------------- aggregation: tb16[n] = h[n] + sum w_e * h[src_e]  (fp32 acc, fp16 out) ----
__global__ __launch_bounds__(256) void gin_agg(const uint* __restrict__ h,
                                               const int* __restrict__ cnt,
                                               const int2* __restrict__ ell,
                                               uint* __restrict__ tb) {
    int node = blockIdx.x * 4 + (threadIdx.x >> 6);
    if (node >= NN) return;
    int lane = threadIdx.x & 63;
    int n = cnt[node];
    if (n > CAP) n = CAP;
    const int2* row = ell + (size_t)node * CAP;
    uint self = h[(size_t)node * 64 + lane];
    float accx = h2f_lo(self), accy = h2f_hi(self);
    float bx = 0.f, by = 0.f;
    int p = 0;
    for (; p + 4 <= n; p += 4) {
        int2 e0 = row[p + 0], e1 = row[p + 1], e2 = row[p + 2], e3 = row[p + 3];
        float w0 = __int_as_float(e0.y), w1 = __int_as_float(e1.y);
        float w2 = __int_as_float(e2.y), w3 = __int_as_float(e3.y);
        uint v0 = h[(size_t)e0.x * 64 + lane];
        uint v1 = h[(size_t)e1.x * 64 + lane];
        uint v2 = h[(size_t)e2.x * 64 + lane];
        uint v3 = h[(size_t)e3.x * 64 + lane];
        accx += w0 * h2f_lo(v0); accy += w0 * h2f_hi(v0);
        bx   += w1 * h2f_lo(v1); by   += w1 * h2f_hi(v1);
        accx += w2 * h2f_lo(v2); accy += w2 * h2f_hi(v2);
        bx   += w3 * h2f_lo(v3); by   += w3 * h2f_hi(v3);
    }
    for (; p < n; ++p) {
        int2 e = row[p];
        float w = __int_as_float(e.y);
        uint v = h[(size_t)e.x * 64 + lane];
        accx += w * h2f_lo(v);
        accy += w * h2f_hi(v);
    }
    accx += bx;
    accy += by;
    tb[(size_t)node * 64 + lane] = (uint)f2h(accx) | ((uint)f2h(accy) << 16);
}

// ---------------- hout(fp16) = relu(tb16 @ W + b) via MFMA 16x16x32 f16 ----------------
// 256 threads = 4 waves; block owns 64 rows; wave owns a 16-row strip x 128 cols.
// Frag layout (gfx950, verified m89/m92/m97): A/B lane holds 8 contiguous K elems,
// k-group = lane>>4; A row / B col = lane&15. C/D: col = lane&15, row = (lane>>4)*4+reg.
__global__ __launch_bounds__(256) void gemm_mfma(const f16* __restrict__ tb,
                                                 const ushort* __restrict__ wp,
                                                 const float* __restrict__ bias,
                                                 ushort* __restrict__ hout) {
    int tid = threadIdx.x;
    int wave = tid >> 6, lane = tid & 63;
    int row0 = blockIdx.x * 64 + wave * 16;
    int n16 = lane & 15;
    int kg = lane >> 4;

    const f16* arow = tb + (size_t)(row0 + n16) * HH + kg * 8;
    f16x8 a0 = *(const f16x8*)(arow + 0);
    f16x8 a1 = *(const f16x8*)(arow + 32);
    f16x8 a2 = *(const f16x8*)(arow + 64);
    f16x8 a3 = *(const f16x8*)(arow + 96);

#pragma unroll
    for (int ct = 0; ct < 8; ct++) {
        const f16* brow = (const f16*)wp + (size_t)(ct * 16 + n16) * HH + kg * 8;
        f16x8 b0 = *(const f16x8*)(brow + 0);
        f16x8 b1 = *(const f16x8*)(brow + 32);
        f16x8 b2 = *(const f16x8*)(brow + 64);
        f16x8 b3 = *(const f16x8*)(brow + 96);
        f32x4 c = {0.f, 0.f, 0.f, 0.f};
        c = __builtin_amdgcn_mfma_f32_16x16x32_f16(a0, b0, c, 0, 0, 0);
        c = __builtin_amdgcn_mfma_f32_16x16x32_f16(a1, b1, c, 0, 0, 0);
        c = __builtin_amdgcn_mfma_f32_16x16x32_f16(a2, b2, c, 0, 0, 0);
        c = __builtin_amdgcn_mfma_f32_16x16x32_f16(a3, b3, c, 0, 0, 0);
        float bv = bias[ct * 16 + n16];
#pragma unroll
        for (int j = 0; j < 4; j++) {
            float o = fmaxf(c[j] + bv, 0.f);
            hout[(size_t)(row0 + kg * 4 + j) * HH + ct * 16 + n16] = f2h(o);
        }
    }
}

// ---------------- fused multipool + readout MLP (one block of 128 per segment) --------
__device__ __forceinline__ float block_sum(float v, float* red, int c) {
    red[c] = v;
    __syncthreads();
#pragma unroll
    for (int off = 64; off > 0; off >>= 1) {
        if (c < off) red[c] += red[c + off];
        __syncthreads();
    }
    float r = red[0];
    __syncthreads();
    return r;
}

__global__ __launch_bounds__(128) void pool_readout(const ushort* __restrict__ h,
    const int* __restrict__ batches,
    const float* __restrict__ w1, const float* __restrict__ b1,
    const float* __restrict__ g1, const float* __restrict__ be1,
    const float* __restrict__ w2, const float* __restrict__ b2,
    const float* __restrict__ g2, const float* __restrict__ be2,
    const float* __restrict__ w3, const float* __restrict__ b3,
    float* __restrict__ out) {
    __shared__ float zr[384];
    __shared__ float red[128];
    __shared__ float v1[128];
    int s = blockIdx.x, c = threadIdx.x;

    // pool: mean/min/max over the 64 gathered rows, column c
    float sum = 0.f, mn = INFINITY, mx = -INFINITY;
    for (int j = 0; j < SEGSZ; j++) {
        int idx = batches[s * SEGSZ + j];
        __half_raw r; r.x = h[(size_t)idx * HH + c];
        float v = __half2float(__half(r));
        sum += v;
        mn = fminf(mn, v);
        mx = fmaxf(mx, v);
    }
    zr[c] = sum * (1.f / SEGSZ);
    zr[128 + c] = mn;
    zr[256 + c] = mx;
    __syncthreads();

    float a = b1[c];
    for (int k = 0; k < 384; k++) a += zr[k] * w1[k * HH + c];
    a = fmaxf(a, 0.f);
    float m = block_sum(a, red, c) * (1.f / HH);
    float d = a - m;
    float var = block_sum(d * d, red, c) * (1.f / HH);
    float v = d * rsqrtf(var + 1e-5f) * g1[c] + be1[c];
    v1[c] = v;
    __syncthreads();

    float a2 = b2[c];
    for (int k = 0; k < HH; k++) a2 += v1[k] * w2[k * HH + c];
    float m2 = block_sum(a2, red, c) * (1.f / HH);
    float d2 = a2 - m2;
    float var2 = block_sum(d2 * d2, red, c) * (1.f / HH);
    float t2 = d2 * rsqrtf(var2 + 1e-5f) * g2[c] + be2[c];
    float z2 = fmaxf(t2, 0.f);

    float tot = block_sum(z2 * w3[c], red, c);
    if (c == 0) out[s] = tot + b3[0];
}

extern "C" void kernel_launch(void* const* d_in, const int* in_sizes, int n_in,
                              void* d_out, int out_size, void* d_ws, size_t ws_size,
                              hipStream_t stream) {
    const float* x        = (const float*)d_in[0];
    const int*   ei       = (const int*)d_in[1];
    const float* ew       = (const float*)d_in[2];
    const int*   batches  = (const int*)d_in[3];
    const float* gw[3]    = {(const float*)d_in[5], (const float*)d_in[7], (const float*)d_in[9]};
    const float* gb[3]    = {(const float*)d_in[6], (const float*)d_in[8], (const float*)d_in[10]};
    const float* r_w1 = (const float*)d_in[11]; const float* r_b1 = (const float*)d_in[12];
    const float* ln1g = (const float*)d_in[13]; const float* ln1b = (const float*)d_in[14];
    const float* r_w2 = (const float*)d_in[15]; const float* r_b2 = (const float*)d_in[16];
    const float* ln2g = (const float*)d_in[17]; const float* ln2b = (const float*)d_in[18];
    const float* r_w3 = (const float*)d_in[19]; const float* r_b3 = (const float*)d_in[20];
    float* out = (float*)d_out;

    // workspace layout
    uint*  h0   = (uint*)d_ws;                       // NN*64 uints (fp16 x2)
    uint*  h1   = h0 + (size_t)NN * 64;              // NN*64
    uint*  tb   = h1 + (size_t)NN * 64;              // NN*64 (fp16 x2)
    uint*  wpk  = tb + (size_t)NN * 64;              // 3*128*128 fp16 = 3*8192 uints... stored as ushort
    int2*  ell  = (int2*)(wpk + 3 * HH * HH / 2);    // NN*CAP int2
    int*   cnt  = (int*)(ell + (size_t)NN * CAP);    // NN

    zero_int<<<(NN + 255) / 256, 256, 0, stream>>>(cnt, NN);
    ell_fill<<<(EE + 255) / 256, 256, 0, stream>>>(ei, ew, cnt, ell);

    wcvt<<<(3 * HH * HH + 255) / 256, 256, 0, stream>>>(gw[0], gw[1], gw[2], (ushort*)wpk);
    build_h0<<<(NN * 64 + 255) / 256, 256, 0, stream>>>(x, h0);
    set_bf<<<(NSEGS * SEGSZ + 255) / 256, 256, 0, stream>>>(batches, (ushort*)h0);

    uint* hin = h0;
    uint* hout = h1;
    for (int l = 0; l < 3; l++) {
        gin_agg<<<(NN + 3) / 4, 256, 0, stream>>>(hin, cnt, ell, tb);
        gemm_mfma<<<NN / 64, 256, 0, stream>>>((const f16*)tb,
                                               (const ushort*)wpk + (size_t)l * HH * HH,
                                               gb[l], (ushort*)hout);
        uint* tmp = hin; hin = hout; hout = tmp;
    }

    pool_readout<<<NSEGS, 128, 0, stream>>>((const ushort*)hin, batches,
                                            r_w1, r_b1, ln1g, ln1b,
                                            r_w2, r_b2, ln2g, ln2b, r_w3, r_b3, out);
}

// Round 8
// 210.455 us; speedup vs baseline: 3.2523x; 1.0160x over previous
//
#include <hip/hip_runtime.h>
#include <hip/hip_fp16.h>

#define NN   40000
#define EE   640000
#define DIN  127
#define HH   128
#define NSEGS 512
#define SEGSZ 64
#define CAP  64          // ELL row capacity (Poisson deg: mean 16, P(>64) ~ 0)

typedef unsigned int uint;
typedef unsigned short ushort;
typedef _Float16 f16;
typedef __attribute__((ext_vector_type(8))) _Float16 f16x8;
typedef __attribute__((ext_vector_type(4))) float f32x4;

__device__ __forceinline__ float h2f_lo(uint v) {
    __half_raw r; r.x = (ushort)(v & 0xffff); return __half2float(__half(r));
}
__device__ __forceinline__ float h2f_hi(uint v) {
    __half_raw r; r.x = (ushort)(v >> 16); return __half2float(__half(r));
}
__device__ __forceinline__ ushort f2h(float f) {
    return __half_as_ushort(__float2half(f));
}

// ---------------- h0 = concat(x, batch_indicator) as fp16 ----------------
__global__ void build_h0(const float* __restrict__ x, uint* __restrict__ h) {
    int t = blockIdx.x * 256 + threadIdx.x;
    if (t >= NN * 64) return;
    int i = t >> 6, q = t & 63;
    int d0 = q << 1;                      // 0..126
    float a = x[i * DIN + d0];
    float b = (d0 + 1 < DIN) ? x[i * DIN + d0 + 1] : 0.f;
    h[t] = (uint)f2h(a) | ((uint)f2h(b) << 16);
}

__global__ void set_bf(const int* __restrict__ batches, ushort* __restrict__ h) {
    int j = blockIdx.x * 256 + threadIdx.x;
    if (j < NSEGS * SEGSZ) h[(size_t)batches[j] * HH + DIN] = 0x3C00;   // fp16 1.0
}

// ---------------- weights fp32 [K][N] -> fp16 N-major [N][K] (B^T) ----------------
__global__ void wcvt(const float* __restrict__ w0, const float* __restrict__ w1,
                     const float* __restrict__ w2, ushort* __restrict__ wp) {
    int t = blockIdx.x * 256 + threadIdx.x;
    if (t >= 3 * HH * HH) return;
    int l = t / (HH * HH);
    int r = t - l * (HH * HH);
    int n = r >> 7, k = r & 127;
    const float* w = (l == 0) ? w0 : (l == 1) ? w1 : w2;
    wp[t] = f2h(w[k * HH + n]);
}

// ---------------- ELL build ----------------
__global__ void zero_int4(int4* __restrict__ p, int n4) {
    int t = blockIdx.x * 256 + threadIdx.x;
    if (t < n4) p[t] = make_int4(0, 0, 0, 0);
}

// counters padded to one per 64B cache line (cnt[d<<4]) to kill same-line
// atomic serialization at the TCC slices. 2 edges/thread for latency overlap.
__global__ void ell_fill(const int* __restrict__ ei, const float* __restrict__ ew,
                         int* __restrict__ cnt, uint* __restrict__ ell) {
    int t = blockIdx.x * 256 + threadIdx.x;
    int e0 = t * 2;
    if (e0 >= EE) return;
    int d0 = ei[EE + e0];
    int d1 = ei[EE + e0 + 1];             // EE even -> e0+1 always valid
    int s0 = ei[e0], s1 = ei[e0 + 1];
    float w0 = ew[e0], w1 = ew[e0 + 1];
    int slot0 = atomicAdd(&cnt[d0 << 4], 1);
    int slot1 = atomicAdd(&cnt[d1 << 4], 1);
    if (slot0 < CAP) ell[(size_t)d0 * CAP + slot0] = (uint)s0 | ((uint)f2h(w0) << 16);
    if (slot1 < CAP) ell[(size_t)d1 * CAP + slot1] = (uint)s1 | ((uint)f2h(w1) << 16);
}

// ---------------- aggregation: tb16[n] = h[n] + sum w_e * h[src_e]  (fp32 acc) ----------
// one wave per node; lane owns one uint = 2 columns; 4-edge unroll
__global__ __launch_bounds__(256) void gin_agg(const uint* __restrict__ h,
                                               const int* __restrict__ cnt,
                                               const uint* __restrict__ ell,
                                               uint* __restrict__ tb) {
    int node = blockIdx.x * 4 + (threadIdx.x >> 6);
    if (node >= NN) return;
    int lane = threadIdx.x & 63;
    int n = cnt[node << 4];
    if (n > CAP) n = CAP;
    const uint* row = ell + (size_t)node * CAP;
    uint self = h[(size_t)node * 64 + lane];
    float accx = h2f_lo(self), accy = h2f_hi(self);
    float bx = 0.f, by = 0.f;
    int p = 0;
    for (; p + 4 <= n; p += 4) {
        uint e0 = row[p + 0], e1 = row[p + 1], e2 = row[p + 2], e3 = row[p + 3];
        float w0 = h2f_hi(e0), w1 = h2f_hi(e1);
        float w2 = h2f_hi(e2), w3 = h2f_hi(e3);
        uint v0 = h[(size_t)(e0 & 0xffff) * 64 + lane];
        uint v1 = h[(size_t)(e1 & 0xffff) * 64 + lane];
        uint v2 = h[(size_t)(e2 & 0xffff) * 64 + lane];
        uint v3 = h[(size_t)(e3 & 0xffff) * 64 + lane];
        accx += w0 * h2f_lo(v0); accy += w0 * h2f_hi(v0);
        bx   += w1 * h2f_lo(v1); by   += w1 * h2f_hi(v1);
        accx += w2 * h2f_lo(v2); accy += w2 * h2f_hi(v2);
        bx   += w3 * h2f_lo(v3); by   += w3 * h2f_hi(v3);
    }
    for (; p < n; ++p) {
        uint e = row[p];
        float w = h2f_hi(e);
        uint v = h[(size_t)(e & 0xffff) * 64 + lane];
        accx += w * h2f_lo(v);
        accy += w * h2f_hi(v);
    }
    accx += bx;
    accy += by;
    tb[(size_t)node * 64 + lane] = (uint)f2h(accx) | ((uint)f2h(accy) << 16);
}

// ---------------- hout(fp16) = relu(tb16 @ W + b) via MFMA 16x16x32 f16 ----------------
// 256 threads = 4 waves; block owns 64 rows; wave owns a 16-row strip x 128 cols.
__global__ __launch_bounds__(256) void gemm_mfma(const f16* __restrict__ tb,
                                                 const ushort* __restrict__ wp,
                                                 const float* __restrict__ bias,
                                                 ushort* __restrict__ hout) {
    int tid = threadIdx.x;
    int wave = tid >> 6, lane = tid & 63;
    int row0 = blockIdx.x * 64 + wave * 16;
    int n16 = lane & 15;
    int kg = lane >> 4;

    const f16* arow = tb + (size_t)(row0 + n16) * HH + kg * 8;
    f16x8 a0 = *(const f16x8*)(arow + 0);
    f16x8 a1 = *(const f16x8*)(arow + 32);
    f16x8 a2 = *(const f16x8*)(arow + 64);
    f16x8 a3 = *(const f16x8*)(arow + 96);

#pragma unroll
    for (int ct = 0; ct < 8; ct++) {
        const f16* brow = (const f16*)wp + (size_t)(ct * 16 + n16) * HH + kg * 8;
        f16x8 b0 = *(const f16x8*)(brow + 0);
        f16x8 b1 = *(const f16x8*)(brow + 32);
        f16x8 b2 = *(const f16x8*)(brow + 64);
        f16x8 b3 = *(const f16x8*)(brow + 96);
        f32x4 c = {0.f, 0.f, 0.f, 0.f};
        c = __builtin_amdgcn_mfma_f32_16x16x32_f16(a0, b0, c, 0, 0, 0);
        c = __builtin_amdgcn_mfma_f32_16x16x32_f16(a1, b1, c, 0, 0, 0);
        c = __builtin_amdgcn_mfma_f32_16x16x32_f16(a2, b2, c, 0, 0, 0);
        c = __builtin_amdgcn_mfma_f32_16x16x32_f16(a3, b3, c, 0, 0, 0);
        float bv = bias[ct * 16 + n16];
#pragma unroll
        for (int j = 0; j < 4; j++) {
            float o = fmaxf(c[j] + bv, 0.f);
            hout[(size_t)(row0 + kg * 4 + j) * HH + ct * 16 + n16] = f2h(o);
        }
    }
}

// ---------------- fused multipool + readout MLP (one block of 128 per segment) --------
__device__ __forceinline__ float block_sum(float v, float* red, int c) {
    red[c] = v;
    __syncthreads();
#pragma unroll
    for (int off = 64; off > 0; off >>= 1) {
        if (c < off) red[c] += red[c + off];
        __syncthreads();
    }
    float r = red[0];
    __syncthreads();
    return r;
}

__global__ __launch_bounds__(128) void pool_readout(const ushort* __restrict__ h,
    const int* __restrict__ batches,
    const float* __restrict__ w1, const float* __restrict__ b1,
    const float* __restrict__ g1, const float* __restrict__ be1,
    const float* __restrict__ w2, const float* __restrict__ b2,
    const float* __restrict__ g2, const float* __restrict__ be2,
    const float* __restrict__ w3, const float* __restrict__ b3,
    float* __restrict__ out) {
    __shared__ float zr[384];
    __shared__ float red[128];
    __shared__ float v1[128];
    int s = blockIdx.x, c = threadIdx.x;

    float sum = 0.f, mn = INFINITY, mx = -INFINITY;
    for (int j = 0; j < SEGSZ; j++) {
        int idx = batches[s * SEGSZ + j];
        __half_raw r; r.x = h[(size_t)idx * HH + c];
        float v = __half2float(__half(r));
        sum += v;
        mn = fminf(mn, v);
        mx = fmaxf(mx, v);
    }
    zr[c] = sum * (1.f / SEGSZ);
    zr[128 + c] = mn;
    zr[256 + c] = mx;
    __syncthreads();

    float a = b1[c];
    for (int k = 0; k < 384; k++) a += zr[k] * w1[k * HH + c];
    a = fmaxf(a, 0.f);
    float m = block_sum(a, red, c) * (1.f / HH);
    float d = a - m;
    float var = block_sum(d * d, red, c) * (1.f / HH);
    float v = d * rsqrtf(var + 1e-5f) * g1[c] + be1[c];
    v1[c] = v;
    __syncthreads();

    float a2 = b2[c];
    for (int k = 0; k < HH; k++) a2 += v1[k] * w2[k * HH + c];
    float m2 = block_sum(a2, red, c) * (1.f / HH);
    float d2 = a2 - m2;
    float var2 = block_sum(d2 * d2, red, c) * (1.f / HH);
    float t2 = d2 * rsqrtf(var2 + 1e-5f) * g2[c] + be2[c];
    float z2 = fmaxf(t2, 0.f);

    float tot = block_sum(z2 * w3[c], red, c);
    if (c == 0) out[s] = tot + b3[0];
}

extern "C" void kernel_launch(void* const* d_in, const int* in_sizes, int n_in,
                              void* d_out, int out_size, void* d_ws, size_t ws_size,
                              hipStream_t stream) {
    const float* x        = (const float*)d_in[0];
    const int*   ei       = (const int*)d_in[1];
    const float* ew       = (const float*)d_in[2];
    const int*   batches  = (const int*)d_in[3];
    const float* gw[3]    = {(const float*)d_in[5], (const float*)d_in[7], (const float*)d_in[9]};
    const float* gb[3]    = {(const float*)d_in[6], (const float*)d_in[8], (const float*)d_in[10]};
    const float* r_w1 = (const float*)d_in[11]; const float* r_b1 = (const float*)d_in[12];
    const float* ln1g = (const float*)d_in[13]; const float* ln1b = (const float*)d_in[14];
    const float* r_w2 = (const float*)d_in[15]; const float* r_b2 = (const float*)d_in[16];
    const float* ln2g = (const float*)d_in[17]; const float* ln2b = (const float*)d_in[18];
    const float* r_w3 = (const float*)d_in[19]; const float* r_b3 = (const float*)d_in[20];
    float* out = (float*)d_out;

    // workspace layout
    uint*  h0   = (uint*)d_ws;                       // NN*64 uints (fp16 x2)
    uint*  h1   = h0 + (size_t)NN * 64;              // NN*64
    uint*  tb   = h1 + (size_t)NN * 64;              // NN*64 (fp16 x2)
    uint*  wpk  = tb + (size_t)NN * 64;              // 3*128*128 fp16 (as ushort)
    uint*  ell  = wpk + 3 * HH * HH / 2;             // NN*CAP uints (packed src|w)
    int*   cnt  = (int*)(ell + (size_t)NN * CAP);    // NN*16 ints (line-padded)

    zero_int4<<<(NN * 16 / 4 + 255) / 256, 256, 0, stream>>>((int4*)cnt, NN * 16 / 4);
    ell_fill<<<(EE / 2 + 255) / 256, 256, 0, stream>>>(ei, ew, cnt, ell);

    wcvt<<<(3 * HH * HH + 255) / 256, 256, 0, stream>>>(gw[0], gw[1], gw[2], (ushort*)wpk);
    build_h0<<<(NN * 64 + 255) / 256, 256, 0, stream>>>(x, h0);
    set_bf<<<(NSEGS * SEGSZ + 255) / 256, 256, 0, stream>>>(batches, (ushort*)h0);

    uint* hin = h0;
    uint* hout = h1;
    for (int l = 0; l < 3; l++) {
        gin_agg<<<(NN + 3) / 4, 256, 0, stream>>>(hin, cnt, ell, tb);
        gemm_mfma<<<NN / 64, 256, 0, stream>>>((const f16*)tb,
                                               (const ushort*)wpk + (size_t)l * HH * HH,
                                               gb[l], (ushort*)hout);
        uint* tmp = hin; hin = hout; hout = tmp;
    }

    pool_readout<<<NSEGS, 128, 0, stream>>>((const ushort*)hin, batches,
                                            r_w1, r_b1, ln1g, ln1b,
                                            r_w2, r_b2, ln2g, ln2b, r_w3, r_b3, out);
}

// Round 9
// 188.761 us; speedup vs baseline: 3.6261x; 1.1149x over previous
//
#include <hip/hip_runtime.h>
#include <hip/hip_fp16.h>

#define NN   40000
#define EE   640000
#define DIN  127
#define HH   128
#define NSEGS 512
#define SEGSZ 64
#define CAP  64          // ELL row capacity (Poisson deg: mean 16, P(>64) ~ 0)
#define NB_ELL 625       // EE/4/256
#define NB_H0  10000     // NN*64/256

typedef unsigned int uint;
typedef unsigned short ushort;
typedef _Float16 f16;
typedef __attribute__((ext_vector_type(8))) _Float16 f16x8;
typedef __attribute__((ext_vector_type(4))) float f32x4;

__device__ __forceinline__ float h2f_lo(uint v) {
    __half_raw r; r.x = (ushort)(v & 0xffff); return __half2float(__half(r));
}
__device__ __forceinline__ float h2f_hi(uint v) {
    __half_raw r; r.x = (ushort)(v >> 16); return __half2float(__half(r));
}
__device__ __forceinline__ ushort f2h(float f) {
    return __half_as_ushort(__float2half(f));
}

// ---------------- prep: zero line-padded counters + weights->fp16 B^T ----------------
__global__ __launch_bounds__(256) void prep(int4* __restrict__ cnt4,
                                            const float* __restrict__ w0,
                                            const float* __restrict__ w1,
                                            const float* __restrict__ w2,
                                            ushort* __restrict__ wp) {
    int t = blockIdx.x * 256 + threadIdx.x;
    if (t < NN * 4) cnt4[t] = make_int4(0, 0, 0, 0);
    if (t < 3 * HH * HH) {
        int l = t / (HH * HH);
        int r = t - l * (HH * HH);
        int n = r >> 7, k = r & 127;
        const float* w = (l == 0) ? w0 : (l == 1) ? w1 : w2;
        wp[t] = f2h(w[k * HH + n]);
    }
}

// ---------------- fused: ELL build (blocks < NB_ELL) || h0 build (rest) ----------------
// ELL: 4 edges/thread, 4 independent atomic chains; counters padded to 64B lines.
// h0: concat(x, 0-indicator-col) as packed fp16.
__global__ __launch_bounds__(256) void ell_h0(const int* __restrict__ ei,
                                              const float* __restrict__ ew,
                                              int* __restrict__ cnt,
                                              uint* __restrict__ ell,
                                              const float* __restrict__ x,
                                              uint* __restrict__ h) {
    int b = blockIdx.x;
    if (b < NB_ELL) {
        int e = (b * 256 + threadIdx.x) * 4;
        int d0 = ei[EE + e + 0], d1 = ei[EE + e + 1];
        int d2 = ei[EE + e + 2], d3 = ei[EE + e + 3];
        int s0 = ei[e + 0], s1 = ei[e + 1], s2 = ei[e + 2], s3 = ei[e + 3];
        float w0 = ew[e + 0], w1 = ew[e + 1], w2 = ew[e + 2], w3 = ew[e + 3];
        int a0 = atomicAdd(&cnt[d0 << 4], 1);
        int a1 = atomicAdd(&cnt[d1 << 4], 1);
        int a2 = atomicAdd(&cnt[d2 << 4], 1);
        int a3 = atomicAdd(&cnt[d3 << 4], 1);
        if (a0 < CAP) ell[(size_t)d0 * CAP + a0] = (uint)s0 | ((uint)f2h(w0) << 16);
        if (a1 < CAP) ell[(size_t)d1 * CAP + a1] = (uint)s1 | ((uint)f2h(w1) << 16);
        if (a2 < CAP) ell[(size_t)d2 * CAP + a2] = (uint)s2 | ((uint)f2h(w2) << 16);
        if (a3 < CAP) ell[(size_t)d3 * CAP + a3] = (uint)s3 | ((uint)f2h(w3) << 16);
    } else {
        int t = (b - NB_ELL) * 256 + threadIdx.x;   // [0, NN*64)
        int i = t >> 6, q = t & 63;
        int d0 = q << 1;                            // 0..126
        float a = x[i * DIN + d0];
        float bb = (d0 + 1 < DIN) ? x[i * DIN + d0 + 1] : 0.f;
        h[t] = (uint)f2h(a) | ((uint)f2h(bb) << 16);
    }
}

__global__ void set_bf(const int* __restrict__ batches, ushort* __restrict__ h) {
    int j = blockIdx.x * 256 + threadIdx.x;
    if (j < NSEGS * SEGSZ) h[(size_t)batches[j] * HH + DIN] = 0x3C00;   // fp16 1.0
}

// ---------------- aggregation: tb16[n] = h[n] + sum w_e * h[src_e]  (fp32 acc) ----------
// 2 nodes per wave: half-wave of 32 lanes owns a node, lane owns 4 cols (uint2).
// Edge descriptors fetched 4-at-a-time via one dwordx4 broadcast per half-wave;
// 4 independent 8B row-loads in flight per half-wave -> 8 per wave.
__global__ __launch_bounds__(256) void gin_agg(const uint* __restrict__ h,
                                               const int* __restrict__ cnt,
                                               const uint* __restrict__ ell,
                                               uint* __restrict__ tb) {
    int tid = threadIdx.x;
    int wid = tid >> 6;
    int lane = tid & 63;
    int half = lane >> 5;
    int l32 = lane & 31;
    int node = blockIdx.x * 8 + wid * 2 + half;     // NN/8 = 5000 blocks exactly
    int n = cnt[node << 4];
    if (n > CAP) n = CAP;
    const uint* row = ell + (size_t)node * CAP;
    uint2 self = *(const uint2*)(h + (size_t)node * 64 + l32 * 2);
    float ax = h2f_lo(self.x), ay = h2f_hi(self.x);
    float az = h2f_lo(self.y), aw = h2f_hi(self.y);
    float bx = 0.f, by = 0.f, bz = 0.f, bw = 0.f;
    int p = 0;
    for (; p + 4 <= n; p += 4) {
        uint4 ee = *(const uint4*)(row + p);
        uint2 v0 = *(const uint2*)(h + (size_t)(ee.x & 0xffff) * 64 + l32 * 2);
        uint2 v1 = *(const uint2*)(h + (size_t)(ee.y & 0xffff) * 64 + l32 * 2);
        uint2 v2 = *(const uint2*)(h + (size_t)(ee.z & 0xffff) * 64 + l32 * 2);
        uint2 v3 = *(const uint2*)(h + (size_t)(ee.w & 0xffff) * 64 + l32 * 2);
        float w0 = h2f_hi(ee.x), w1 = h2f_hi(ee.y);
        float w2 = h2f_hi(ee.z), w3 = h2f_hi(ee.w);
        ax += w0 * h2f_lo(v0.x); ay += w0 * h2f_hi(v0.x);
        az += w0 * h2f_lo(v0.y); aw += w0 * h2f_hi(v0.y);
        bx += w1 * h2f_lo(v1.x); by += w1 * h2f_hi(v1.x);
        bz += w1 * h2f_lo(v1.y); bw += w1 * h2f_hi(v1.y);
        ax += w2 * h2f_lo(v2.x); ay += w2 * h2f_hi(v2.x);
        az += w2 * h2f_lo(v2.y); aw += w2 * h2f_hi(v2.y);
        bx += w3 * h2f_lo(v3.x); by += w3 * h2f_hi(v3.x);
        bz += w3 * h2f_lo(v3.y); bw += w3 * h2f_hi(v3.y);
    }
    for (; p < n; ++p) {
        uint e = row[p];
        float w = h2f_hi(e);
        uint2 v = *(const uint2*)(h + (size_t)(e & 0xffff) * 64 + l32 * 2);
        ax += w * h2f_lo(v.x); ay += w * h2f_hi(v.x);
        az += w * h2f_lo(v.y); aw += w * h2f_hi(v.y);
    }
    ax += bx; ay += by; az += bz; aw += bw;
    uint2 o;
    o.x = (uint)f2h(ax) | ((uint)f2h(ay) << 16);
    o.y = (uint)f2h(az) | ((uint)f2h(aw) << 16);
    *(uint2*)(tb + (size_t)node * 64 + l32 * 2) = o;
}

// ---------------- hout(fp16) = relu(tb16 @ W + b) via MFMA 16x16x32 f16 ----------------
// 256 threads = 4 waves; block owns 64 rows; wave owns a 16-row strip x 128 cols.
__global__ __launch_bounds__(256) void gemm_mfma(const f16* __restrict__ tb,
                                                 const ushort* __restrict__ wp,
                                                 const float* __restrict__ bias,
                                                 ushort* __restrict__ hout) {
    int tid = threadIdx.x;
    int wave = tid >> 6, lane = tid & 63;
    int row0 = blockIdx.x * 64 + wave * 16;
    int n16 = lane & 15;
    int kg = lane >> 4;

    const f16* arow = tb + (size_t)(row0 + n16) * HH + kg * 8;
    f16x8 a0 = *(const f16x8*)(arow + 0);
    f16x8 a1 = *(const f16x8*)(arow + 32);
    f16x8 a2 = *(const f16x8*)(arow + 64);
    f16x8 a3 = *(const f16x8*)(arow + 96);

#pragma unroll
    for (int ct = 0; ct < 8; ct++) {
        const f16* brow = (const f16*)wp + (size_t)(ct * 16 + n16) * HH + kg * 8;
        f16x8 b0 = *(const f16x8*)(brow + 0);
        f16x8 b1 = *(const f16x8*)(brow + 32);
        f16x8 b2 = *(const f16x8*)(brow + 64);
        f16x8 b3 = *(const f16x8*)(brow + 96);
        f32x4 c = {0.f, 0.f, 0.f, 0.f};
        c = __builtin_amdgcn_mfma_f32_16x16x32_f16(a0, b0, c, 0, 0, 0);
        c = __builtin_amdgcn_mfma_f32_16x16x32_f16(a1, b1, c, 0, 0, 0);
        c = __builtin_amdgcn_mfma_f32_16x16x32_f16(a2, b2, c, 0, 0, 0);
        c = __builtin_amdgcn_mfma_f32_16x16x32_f16(a3, b3, c, 0, 0, 0);
        float bv = bias[ct * 16 + n16];
#pragma unroll
        for (int j = 0; j < 4; j++) {
            float o = fmaxf(c[j] + bv, 0.f);
            hout[(size_t)(row0 + kg * 4 + j) * HH + ct * 16 + n16] = f2h(o);
        }
    }
}

// ---------------- fused multipool + readout MLP (one block of 128 per segment) --------
__device__ __forceinline__ float block_sum(float v, float* red, int c) {
    red[c] = v;
    __syncthreads();
#pragma unroll
    for (int off = 64; off > 0; off >>= 1) {
        if (c < off) red[c] += red[c + off];
        __syncthreads();
    }
    float r = red[0];
    __syncthreads();
    return r;
}

__global__ __launch_bounds__(128) void pool_readout(const ushort* __restrict__ h,
    const int* __restrict__ batches,
    const float* __restrict__ w1, const float* __restrict__ b1,
    const float* __restrict__ g1, const float* __restrict__ be1,
    const float* __restrict__ w2, const float* __restrict__ b2,
    const float* __restrict__ g2, const float* __restrict__ be2,
    const float* __restrict__ w3, const float* __restrict__ b3,
    float* __restrict__ out) {
    __shared__ float zr[384];
    __shared__ float red[128];
    __shared__ float v1[128];
    int s = blockIdx.x, c = threadIdx.x;

    float sum = 0.f, mn = INFINITY, mx = -INFINITY;
    for (int j = 0; j < SEGSZ; j++) {
        int idx = batches[s * SEGSZ + j];
        __half_raw r; r.x = h[(size_t)idx * HH + c];
        float v = __half2float(__half(r));
        sum += v;
        mn = fminf(mn, v);
        mx = fmaxf(mx, v);
    }
    zr[c] = sum * (1.f / SEGSZ);
    zr[128 + c] = mn;
    zr[256 + c] = mx;
    __syncthreads();

    float a = b1[c];
    for (int k = 0; k < 384; k++) a += zr[k] * w1[k * HH + c];
    a = fmaxf(a, 0.f);
    float m = block_sum(a, red, c) * (1.f / HH);
    float d = a - m;
    float var = block_sum(d * d, red, c) * (1.f / HH);
    float v = d * rsqrtf(var + 1e-5f) * g1[c] + be1[c];
    v1[c] = v;
    __syncthreads();

    float a2 = b2[c];
    for (int k = 0; k < HH; k++) a2 += v1[k] * w2[k * HH + c];
    float m2 = block_sum(a2, red, c) * (1.f / HH);
    float d2 = a2 - m2;
    float var2 = block_sum(d2 * d2, red, c) * (1.f / HH);
    float t2 = d2 * rsqrtf(var2 + 1e-5f) * g2[c] + be2[c];
    float z2 = fmaxf(t2, 0.f);

    float tot = block_sum(z2 * w3[c], red, c);
    if (c == 0) out[s] = tot + b3[0];
}

extern "C" void kernel_launch(void* const* d_in, const int* in_sizes, int n_in,
                              void* d_out, int out_size, void* d_ws, size_t ws_size,
                              hipStream_t stream) {
    const float* x        = (const float*)d_in[0];
    const int*   ei       = (const int*)d_in[1];
    const float* ew       = (const float*)d_in[2];
    const int*   batches  = (const int*)d_in[3];
    const float* gw[3]    = {(const float*)d_in[5], (const float*)d_in[7], (const float*)d_in[9]};
    const float* gb[3]    = {(const float*)d_in[6], (const float*)d_in[8], (const float*)d_in[10]};
    const float* r_w1 = (const float*)d_in[11]; const float* r_b1 = (const float*)d_in[12];
    const float* ln1g = (const float*)d_in[13]; const float* ln1b = (const float*)d_in[14];
    const float* r_w2 = (const float*)d_in[15]; const float* r_b2 = (const float*)d_in[16];
    const float* ln2g = (const float*)d_in[17]; const float* ln2b = (const float*)d_in[18];
    const float* r_w3 = (const float*)d_in[19]; const float* r_b3 = (const float*)d_in[20];
    float* out = (float*)d_out;

    // workspace layout
    uint*  h0   = (uint*)d_ws;                       // NN*64 uints (fp16 x2)
    uint*  h1   = h0 + (size_t)NN * 64;              // NN*64
    uint*  tb   = h1 + (size_t)NN * 64;              // NN*64 (fp16 x2)
    uint*  wpk  = tb + (size_t)NN * 64;              // 3*128*128 fp16 (as ushort)
    uint*  ell  = wpk + 3 * HH * HH / 2;             // NN*CAP uints (packed src|w)
    int*   cnt  = (int*)(ell + (size_t)NN * CAP);    // NN*16 ints (line-padded)

    prep<<<625, 256, 0, stream>>>((int4*)cnt, gw[0], gw[1], gw[2], (ushort*)wpk);
    ell_h0<<<NB_ELL + NB_H0, 256, 0, stream>>>(ei, ew, cnt, ell, x, h0);
    set_bf<<<(NSEGS * SEGSZ + 255) / 256, 256, 0, stream>>>(batches, (ushort*)h0);

    uint* hin = h0;
    uint* hout = h1;
    for (int l = 0; l < 3; l++) {
        gin_agg<<<NN / 8, 256, 0, stream>>>(hin, cnt, ell, tb);
        gemm_mfma<<<NN / 64, 256, 0, stream>>>((const f16*)tb,
                                               (const ushort*)wpk + (size_t)l * HH * HH,
                                               gb[l], (ushort*)hout);
        uint* tmp = hin; hin = hout; hout = tmp;
    }

    pool_readout<<<NSEGS, 128, 0, stream>>>((const ushort*)hin, batches,
                                            r_w1, r_b1, ln1g, ln1b,
                                            r_w2, r_b2, ln2g, ln2b, r_w3, r_b3, out);
}

// Round 10
// 185.311 us; speedup vs baseline: 3.6936x; 1.0186x over previous
//
#include <hip/hip_runtime.h>
#include <hip/hip_fp16.h>

#define NN   40000
#define EE   640000
#define DIN  127
#define HH   128
#define NSEGS 512
#define SEGSZ 64
#define CAP  64          // ELL row capacity (Poisson deg: mean 16, P(>64) ~ 0)
#define NB_ELL 625       // EE/4/256
#define NB_H0  10000     // NN*64/256

typedef unsigned int uint;
typedef unsigned short ushort;
typedef _Float16 f16;
typedef __attribute__((ext_vector_type(8))) _Float16 f16x8;
typedef __attribute__((ext_vector_type(4))) float f32x4;

__device__ __forceinline__ float h2f_lo(uint v) {
    __half_raw r; r.x = (ushort)(v & 0xffff); return __half2float(__half(r));
}
__device__ __forceinline__ float h2f_hi(uint v) {
    __half_raw r; r.x = (ushort)(v >> 16); return __half2float(__half(r));
}
__device__ __forceinline__ ushort f2h(float f) {
    return __half_as_ushort(__float2half(f));
}

// ---------------- prep: zero line-padded counters + weights->fp16 B^T ----------------
__global__ __launch_bounds__(256) void prep(int4* __restrict__ cnt4,
                                            const float* __restrict__ w0,
                                            const float* __restrict__ w1,
                                            const float* __restrict__ w2,
                                            ushort* __restrict__ wp) {
    int t = blockIdx.x * 256 + threadIdx.x;
    if (t < NN * 4) cnt4[t] = make_int4(0, 0, 0, 0);
    if (t < 3 * HH * HH) {
        int l = t / (HH * HH);
        int r = t - l * (HH * HH);
        int n = r >> 7, k = r & 127;
        const float* w = (l == 0) ? w0 : (l == 1) ? w1 : w2;
        wp[t] = f2h(w[k * HH + n]);
    }
}

// ---------------- fused: ELL build (blocks < NB_ELL) || h0 build (rest) ----------------
__global__ __launch_bounds__(256) void ell_h0(const int* __restrict__ ei,
                                              const float* __restrict__ ew,
                                              int* __restrict__ cnt,
                                              uint* __restrict__ ell,
                                              const float* __restrict__ x,
                                              uint* __restrict__ h) {
    int b = blockIdx.x;
    if (b < NB_ELL) {
        int e = (b * 256 + threadIdx.x) * 4;
        int d0 = ei[EE + e + 0], d1 = ei[EE + e + 1];
        int d2 = ei[EE + e + 2], d3 = ei[EE + e + 3];
        int s0 = ei[e + 0], s1 = ei[e + 1], s2 = ei[e + 2], s3 = ei[e + 3];
        float w0 = ew[e + 0], w1 = ew[e + 1], w2 = ew[e + 2], w3 = ew[e + 3];
        int a0 = atomicAdd(&cnt[d0 << 4], 1);
        int a1 = atomicAdd(&cnt[d1 << 4], 1);
        int a2 = atomicAdd(&cnt[d2 << 4], 1);
        int a3 = atomicAdd(&cnt[d3 << 4], 1);
        if (a0 < CAP) ell[(size_t)d0 * CAP + a0] = (uint)s0 | ((uint)f2h(w0) << 16);
        if (a1 < CAP) ell[(size_t)d1 * CAP + a1] = (uint)s1 | ((uint)f2h(w1) << 16);
        if (a2 < CAP) ell[(size_t)d2 * CAP + a2] = (uint)s2 | ((uint)f2h(w2) << 16);
        if (a3 < CAP) ell[(size_t)d3 * CAP + a3] = (uint)s3 | ((uint)f2h(w3) << 16);
    } else {
        int t = (b - NB_ELL) * 256 + threadIdx.x;   // [0, NN*64)
        int i = t >> 6, q = t & 63;
        int d0 = q << 1;                            // 0..126
        float a = x[i * DIN + d0];
        float bb = (d0 + 1 < DIN) ? x[i * DIN + d0 + 1] : 0.f;
        h[t] = (uint)f2h(a) | ((uint)f2h(bb) << 16);
    }
}

__global__ void set_bf(const int* __restrict__ batches, ushort* __restrict__ h) {
    int j = blockIdx.x * 256 + threadIdx.x;
    if (j < NSEGS * SEGSZ) h[(size_t)batches[j] * HH + DIN] = 0x3C00;   // fp16 1.0
}

// ---------------- fused GIN layer: aggregate 16 rows -> swizzled LDS -> MFMA GEMM ------
// 2500 blocks x 256 threads (4 waves). Phase A: 2 nodes/wave concurrent (half-wave
// owns a node, lane owns 4 cols) x 2 iters = 16 rows into LDS, XOR-swizzled
// (word ^= (row&7)<<2) so phase-B b128 A-frag reads are bank-conflict-free.
// Phase B: wave owns cols [wave*32, wave*32+32): 2 col-tiles x 4 K-steps of
// mfma_f32_16x16x32_f16; bias+relu; fp16 store.
__global__ __launch_bounds__(256) void gin_layer(const uint* __restrict__ h,
                                                 const int* __restrict__ cnt,
                                                 const uint* __restrict__ ell,
                                                 const ushort* __restrict__ wp,
                                                 const float* __restrict__ bias,
                                                 ushort* __restrict__ hout) {
    __shared__ __align__(16) uint lds[16 * 64];   // 16 rows x 128 f16, swizzled
    int tid = threadIdx.x;
    int wave = tid >> 6, lane = tid & 63;
    int half = lane >> 5, l32 = lane & 31;

#pragma unroll
    for (int it = 0; it < 2; ++it) {
        int ni = it * 8 + wave * 2 + half;          // 0..15
        int node = blockIdx.x * 16 + ni;
        int n = cnt[node << 4];
        if (n > CAP) n = CAP;
        const uint* row = ell + (size_t)node * CAP;
        uint2 self = *(const uint2*)(h + (size_t)node * 64 + l32 * 2);
        float ax = h2f_lo(self.x), ay = h2f_hi(self.x);
        float az = h2f_lo(self.y), aw = h2f_hi(self.y);
        float bx = 0.f, by = 0.f, bz = 0.f, bw = 0.f;
        int p = 0;
        for (; p + 4 <= n; p += 4) {
            uint4 ee = *(const uint4*)(row + p);
            uint2 v0 = *(const uint2*)(h + (size_t)(ee.x & 0xffff) * 64 + l32 * 2);
            uint2 v1 = *(const uint2*)(h + (size_t)(ee.y & 0xffff) * 64 + l32 * 2);
            uint2 v2 = *(const uint2*)(h + (size_t)(ee.z & 0xffff) * 64 + l32 * 2);
            uint2 v3 = *(const uint2*)(h + (size_t)(ee.w & 0xffff) * 64 + l32 * 2);
            float w0 = h2f_hi(ee.x), w1 = h2f_hi(ee.y);
            float w2 = h2f_hi(ee.z), w3 = h2f_hi(ee.w);
            ax += w0 * h2f_lo(v0.x); ay += w0 * h2f_hi(v0.x);
            az += w0 * h2f_lo(v0.y); aw += w0 * h2f_hi(v0.y);
            bx += w1 * h2f_lo(v1.x); by += w1 * h2f_hi(v1.x);
            bz += w1 * h2f_lo(v1.y); bw += w1 * h2f_hi(v1.y);
            ax += w2 * h2f_lo(v2.x); ay += w2 * h2f_hi(v2.x);
            az += w2 * h2f_lo(v2.y); aw += w2 * h2f_hi(v2.y);
            bx += w3 * h2f_lo(v3.x); by += w3 * h2f_hi(v3.x);
            bz += w3 * h2f_lo(v3.y); bw += w3 * h2f_hi(v3.y);
        }
        for (; p < n; ++p) {
            uint e = row[p];
            float w = h2f_hi(e);
            uint2 v = *(const uint2*)(h + (size_t)(e & 0xffff) * 64 + l32 * 2);
            ax += w * h2f_lo(v.x); ay += w * h2f_hi(v.x);
            az += w * h2f_lo(v.y); aw += w * h2f_hi(v.y);
        }
        ax += bx; ay += by; az += bz; aw += bw;
        uint2 o;
        o.x = (uint)f2h(ax) | ((uint)f2h(ay) << 16);
        o.y = (uint)f2h(az) | ((uint)f2h(aw) << 16);
        int wsw = (l32 * 2) ^ ((ni & 7) << 2);      // swizzled word offset in row
        *(uint2*)(&lds[ni * 64 + wsw]) = o;
    }
    __syncthreads();

    int n16 = lane & 15, kg = lane >> 4;
    // A-frags: rows 0..15, K-step s covers f16 cols s*32 + kg*8 .. +8
    f16x8 a[4];
#pragma unroll
    for (int s = 0; s < 4; ++s) {
        int w = (s * 16 + kg * 4) ^ ((n16 & 7) << 2);
        a[s] = *(const f16x8*)(&lds[n16 * 64 + w]);
    }
    int row0 = blockIdx.x * 16;
#pragma unroll
    for (int t = 0; t < 2; ++t) {
        int ct = wave * 2 + t;
        const f16* brow = (const f16*)wp + (size_t)(ct * 16 + n16) * HH + kg * 8;
        f16x8 b0 = *(const f16x8*)(brow + 0);
        f16x8 b1 = *(const f16x8*)(brow + 32);
        f16x8 b2 = *(const f16x8*)(brow + 64);
        f16x8 b3 = *(const f16x8*)(brow + 96);
        f32x4 c = {0.f, 0.f, 0.f, 0.f};
        c = __builtin_amdgcn_mfma_f32_16x16x32_f16(a[0], b0, c, 0, 0, 0);
        c = __builtin_amdgcn_mfma_f32_16x16x32_f16(a[1], b1, c, 0, 0, 0);
        c = __builtin_amdgcn_mfma_f32_16x16x32_f16(a[2], b2, c, 0, 0, 0);
        c = __builtin_amdgcn_mfma_f32_16x16x32_f16(a[3], b3, c, 0, 0, 0);
        float bv = bias[ct * 16 + n16];
#pragma unroll
        for (int j = 0; j < 4; j++) {
            float o = fmaxf(c[j] + bv, 0.f);
            hout[(size_t)(row0 + kg * 4 + j) * HH + ct * 16 + n16] = f2h(o);
        }
    }
}

// ---------------- fused multipool + readout MLP (one block of 128 per segment) --------
__device__ __forceinline__ float block_sum(float v, float* red, int c) {
    red[c] = v;
    __syncthreads();
#pragma unroll
    for (int off = 64; off > 0; off >>= 1) {
        if (c < off) red[c] += red[c + off];
        __syncthreads();
    }
    float r = red[0];
    __syncthreads();
    return r;
}

__global__ __launch_bounds__(128) void pool_readout(const ushort* __restrict__ h,
    const int* __restrict__ batches,
    const float* __restrict__ w1, const float* __restrict__ b1,
    const float* __restrict__ g1, const float* __restrict__ be1,
    const float* __restrict__ w2, const float* __restrict__ b2,
    const float* __restrict__ g2, const float* __restrict__ be2,
    const float* __restrict__ w3, const float* __restrict__ b3,
    float* __restrict__ out) {
    __shared__ float zr[384];
    __shared__ float red[128];
    __shared__ float v1[128];
    int s = blockIdx.x, c = threadIdx.x;

    float sum = 0.f, mn = INFINITY, mx = -INFINITY;
    for (int j = 0; j < SEGSZ; j++) {
        int idx = batches[s * SEGSZ + j];
        __half_raw r; r.x = h[(size_t)idx * HH + c];
        float v = __half2float(__half(r));
        sum += v;
        mn = fminf(mn, v);
        mx = fmaxf(mx, v);
    }
    zr[c] = sum * (1.f / SEGSZ);
    zr[128 + c] = mn;
    zr[256 + c] = mx;
    __syncthreads();

    float a = b1[c];
    for (int k = 0; k < 384; k++) a += zr[k] * w1[k * HH + c];
    a = fmaxf(a, 0.f);
    float m = block_sum(a, red, c) * (1.f / HH);
    float d = a - m;
    float var = block_sum(d * d, red, c) * (1.f / HH);
    float v = d * rsqrtf(var + 1e-5f) * g1[c] + be1[c];
    v1[c] = v;
    __syncthreads();

    float a2 = b2[c];
    for (int k = 0; k < HH; k++) a2 += v1[k] * w2[k * HH + c];
    float m2 = block_sum(a2, red, c) * (1.f / HH);
    float d2 = a2 - m2;
    float var2 = block_sum(d2 * d2, red, c) * (1.f / HH);
    float t2 = d2 * rsqrtf(var2 + 1e-5f) * g2[c] + be2[c];
    float z2 = fmaxf(t2, 0.f);

    float tot = block_sum(z2 * w3[c], red, c);
    if (c == 0) out[s] = tot + b3[0];
}

extern "C" void kernel_launch(void* const* d_in, const int* in_sizes, int n_in,
                              void* d_out, int out_size, void* d_ws, size_t ws_size,
                              hipStream_t stream) {
    const float* x        = (const float*)d_in[0];
    const int*   ei       = (const int*)d_in[1];
    const float* ew       = (const float*)d_in[2];
    const int*   batches  = (const int*)d_in[3];
    const float* gw[3]    = {(const float*)d_in[5], (const float*)d_in[7], (const float*)d_in[9]};
    const float* gb[3]    = {(const float*)d_in[6], (const float*)d_in[8], (const float*)d_in[10]};
    const float* r_w1 = (const float*)d_in[11]; const float* r_b1 = (const float*)d_in[12];
    const float* ln1g = (const float*)d_in[13]; const float* ln1b = (const float*)d_in[14];
    const float* r_w2 = (const float*)d_in[15]; const float* r_b2 = (const float*)d_in[16];
    const float* ln2g = (const float*)d_in[17]; const float* ln2b = (const float*)d_in[18];
    const float* r_w3 = (const float*)d_in[19]; const float* r_b3 = (const float*)d_in[20];
    float* out = (float*)d_out;

    // workspace layout
    uint*  h0   = (uint*)d_ws;                       // NN*64 uints (fp16 x2)
    uint*  h1   = h0 + (size_t)NN * 64;              // NN*64
    uint*  wpk  = h1 + (size_t)NN * 64;              // 3*128*128 fp16 (as ushort)
    uint*  ell  = wpk + 3 * HH * HH / 2;             // NN*CAP uints (packed src|w)
    int*   cnt  = (int*)(ell + (size_t)NN * CAP);    // NN*16 ints (line-padded)

    prep<<<625, 256, 0, stream>>>((int4*)cnt, gw[0], gw[1], gw[2], (ushort*)wpk);
    ell_h0<<<NB_ELL + NB_H0, 256, 0, stream>>>(ei, ew, cnt, ell, x, h0);
    set_bf<<<(NSEGS * SEGSZ + 255) / 256, 256, 0, stream>>>(batches, (ushort*)h0);

    uint* hin = h0;
    uint* hout = h1;
    for (int l = 0; l < 3; l++) {
        gin_layer<<<NN / 16, 256, 0, stream>>>(hin, cnt, ell,
                                               (const ushort*)wpk + (size_t)l * HH * HH,
                                               gb[l], (ushort*)hout);
        uint* tmp = hin; hin = hout; hout = tmp;
    }

    pool_readout<<<NSEGS, 128, 0, stream>>>((const ushort*)hin, batches,
                                            r_w1, r_b1, ln1g, ln1b,
                                            r_w2, r_b2, ln2g, ln2b, r_w3, r_b3, out);
}